// Round 1
// baseline (5756.691 us; speedup 1.0000x reference)
//
#include <hip/hip_runtime.h>

// ---------------------------------------------------------------------------
// Pointer-generator decoder (GRU + dual Bahdanau attention + copy mechanism)
// B=32 S=400 H=512 E=300 Vs=200 T=32 EN=50000 V=50200
// Strategy: batched bf16-MFMA precompute, 32 light sequential steps,
// deferred batched vocab GEMM [1024x512x50000] with fused exp/rowsum.
// ---------------------------------------------------------------------------

typedef __attribute__((ext_vector_type(8))) short short8;
typedef __attribute__((ext_vector_type(4))) float f32x4;

__device__ __forceinline__ float bf2f(unsigned short u) {
  return __uint_as_float(((unsigned)u) << 16);
}
__device__ __forceinline__ unsigned short f2bf(float f) {
  unsigned x = __float_as_uint(f);
  unsigned r = x + 0x7fffu + ((x >> 16) & 1u);
  return (unsigned short)(r >> 16);
}
__device__ __forceinline__ float fsigmoid(float x) { return 1.f / (1.f + __expf(-x)); }
__device__ __forceinline__ float ftanh(float x) {
  float t = __expf(-2.f * fabsf(x));
  float r = (1.f - t) / (1.f + t);
  return x >= 0.f ? r : -r;
}

// --------------------------- generic small kernels -------------------------

// fp32 -> bf16 cast, vectorized, grid-stride over n4 float4s
__global__ __launch_bounds__(256) void k_cast_f2b(const float* __restrict__ src,
                                                  unsigned short* __restrict__ dst,
                                                  int n4) {
  int stride = gridDim.x * blockDim.x;
  for (int i = blockIdx.x * blockDim.x + threadIdx.x; i < n4; i += stride) {
    float4 v = ((const float4*)src)[i];
    ushort4 o;
    o.x = f2bf(v.x); o.y = f2bf(v.y); o.z = f2bf(v.z); o.w = f2bf(v.w);
    ((ushort4*)dst)[i] = o;
  }
}

// transpose + cast: src [R][C] f32 -> dst [C][Rpad] bf16 (zero pad rows >= R)
__global__ __launch_bounds__(256) void k_tcast(const float* __restrict__ src,
                                               unsigned short* __restrict__ dst,
                                               int R, int C, int Rpad) {
  __shared__ float tile[32][33];
  int c0 = blockIdx.x * 32, r0 = blockIdx.y * 32;
  int tx = threadIdx.x & 31, ty = threadIdx.x >> 5;
#pragma unroll
  for (int i = 0; i < 4; ++i) {
    int r = r0 + ty + i * 8, c = c0 + tx;
    tile[ty + i * 8][tx] = (r < R && c < C) ? src[(size_t)r * C + c] : 0.f;
  }
  __syncthreads();
#pragma unroll
  for (int i = 0; i < 4; ++i) {
    int c = c0 + ty + i * 8, rr = r0 + tx;
    if (c < C && rr < Rpad) dst[(size_t)c * Rpad + rr] = f2bf(tile[tx][ty + i * 8]);
  }
}

// cast rows [R][C] f32 -> [R][Cpad] bf16 with zero pad (W_ih is already [N][K])
__global__ __launch_bounds__(64) void k_castpad(const float* __restrict__ src,
                                                unsigned short* __restrict__ dst,
                                                int C, int Cpad) {
  int row = blockIdx.x;
  for (int k = threadIdx.x; k < Cpad; k += 64)
    dst[(size_t)row * Cpad + k] = (k < C) ? f2bf(src[(size_t)row * C + k]) : (unsigned short)0;
}

// gather prev-token embeddings -> xe_bf [1024][320] (row r = t*32+b)
__global__ __launch_bounds__(64) void k_gather_xe(const float* __restrict__ W_embed,
                                                  const int* __restrict__ tgt,
                                                  unsigned short* __restrict__ xe) {
  int r = blockIdx.x;
  int t = r >> 5, b = r & 31;
  int tok = (t == 0) ? 1 : tgt[b * 32 + (t - 1)];
  const float* src = W_embed + (size_t)tok * 300;
  for (int k = threadIdx.x; k < 320; k += 64)
    xe[(size_t)r * 320 + k] = (k < 300) ? f2bf(src[k]) : (unsigned short)0;
}

// gather user-specific vocab embeddings -> uve_bf [6400][320]
__global__ __launch_bounds__(64) void k_gather_uve(const float* __restrict__ W_embed,
                                                   const int* __restrict__ sv,
                                                   unsigned short* __restrict__ uve) {
  int row = blockIdx.x;  // b*200+v
  int tok = sv[row];
  const float* src = W_embed + (size_t)tok * 300;
  for (int k = threadIdx.x; k < 320; k += 64)
    uve[(size_t)row * 320 + k] = (k < 300) ? f2bf(src[k]) : (unsigned short)0;
}

// --------------------------- MFMA GEMMs ------------------------------------
// Big GEMM: A [M][K] bf16, BT [N][K] bf16, BM=256 BN=128 BK=32, 512 threads.
// MODE 0: out bf16 [M][N] = A@B + bias (bias[n])
// MODE 1: out fp32 exp(logit) scattered to out[(r&31)*32+(r>>5)][c] of [1024][50200],
//         atomic row-sum accumulation into rowsum[r].
template <int MODE>
__global__ __launch_bounds__(512) void gemm_bt(const unsigned short* __restrict__ A,
                                               const unsigned short* __restrict__ BT,
                                               int M, int N, int K, int Ntiles,
                                               const float* __restrict__ bias,
                                               unsigned short* __restrict__ outB,
                                               float* __restrict__ outF,
                                               float* __restrict__ rowsum) {
  __shared__ unsigned short As[256 * 32];
  __shared__ unsigned short Bs[128 * 32];
  __shared__ float rs[256];
  const int tid = threadIdx.x;
  const int lane = tid & 63, wid = tid >> 6;
  const int wr = wid >> 1, wc = wid & 1;
  const int bx = blockIdx.x;
  const int mt = bx / Ntiles, nt = bx - mt * Ntiles;
  const int m0 = mt * 256, n0 = nt * 128;
  f32x4 acc[4][4] = {};
  for (int kk = 0; kk < K; kk += 32) {
    uint4 av0, av1, bv;
    {
      int c = tid, row = c >> 2, c8 = (c & 3) * 8;
      av0 = *(const uint4*)(A + (size_t)(m0 + row) * K + kk + c8);
      c = tid + 512; row = c >> 2; c8 = (c & 3) * 8;
      av1 = *(const uint4*)(A + (size_t)(m0 + row) * K + kk + c8);
      c = tid; row = c >> 2; c8 = (c & 3) * 8;
      int nr = n0 + row; if (nr > N - 1) nr = N - 1;
      bv = *(const uint4*)(BT + (size_t)nr * K + kk + c8);
    }
    __syncthreads();
    ((uint4*)As)[tid] = av0;
    ((uint4*)As)[tid + 512] = av1;
    ((uint4*)Bs)[tid] = bv;
    __syncthreads();
    short8 af[4], bfr[4];
#pragma unroll
    for (int m = 0; m < 4; ++m)
      af[m] = *(const short8*)(As + (wr * 64 + m * 16 + (lane & 15)) * 32 + (lane >> 4) * 8);
#pragma unroll
    for (int n = 0; n < 4; ++n)
      bfr[n] = *(const short8*)(Bs + (wc * 64 + n * 16 + (lane & 15)) * 32 + (lane >> 4) * 8);
#pragma unroll
    for (int m = 0; m < 4; ++m)
#pragma unroll
      for (int n = 0; n < 4; ++n)
        acc[m][n] = __builtin_amdgcn_mfma_f32_16x16x32_bf16(af[m], bfr[n], acc[m][n], 0, 0, 0);
  }
  if (MODE == 0) {
#pragma unroll
    for (int m = 0; m < 4; ++m)
#pragma unroll
      for (int n = 0; n < 4; ++n)
#pragma unroll
        for (int reg = 0; reg < 4; ++reg) {
          int r = m0 + wr * 64 + m * 16 + (lane >> 4) * 4 + reg;
          int c = n0 + wc * 64 + n * 16 + (lane & 15);
          outB[(size_t)r * N + c] = f2bf(acc[m][n][reg] + bias[c]);
        }
  } else {
    if (tid < 256) rs[tid] = 0.f;
    __syncthreads();
#pragma unroll
    for (int m = 0; m < 4; ++m) {
#pragma unroll
      for (int reg = 0; reg < 4; ++reg) {
        int rloc = wr * 64 + m * 16 + (lane >> 4) * 4 + reg;
        int r = m0 + rloc;
        size_t obase = (size_t)((r & 31) * 32 + (r >> 5)) * 50200;
        float s = 0.f;
#pragma unroll
        for (int n = 0; n < 4; ++n) {
          int c = n0 + wc * 64 + n * 16 + (lane & 15);
          if (c < N) {
            float e = __expf(acc[m][n][reg]);
            outF[obase + c] = e;
            s += e;
          }
        }
        s += __shfl_xor(s, 1, 64); s += __shfl_xor(s, 2, 64);
        s += __shfl_xor(s, 4, 64); s += __shfl_xor(s, 8, 64);
        if ((lane & 15) == 0) atomicAdd(&rs[rloc], s);
      }
    }
    __syncthreads();
    if (tid < 256) atomicAdd(&rowsum[m0 + tid], rs[tid]);
  }
}

// Small-M GEMM: A [32][K] bf16, BT [N][K] bf16, BN=128, 256 threads (4 waves).
// MODE 0: outF [32][N] fp32 = A@B + bias
// MODE 1: outB [32][N] bf16 = tanh(A@B)
template <int MODE>
__global__ __launch_bounds__(256) void gemm_ms(const unsigned short* __restrict__ A,
                                               const unsigned short* __restrict__ BT,
                                               int N, int K,
                                               const float* __restrict__ bias,
                                               float* __restrict__ outF,
                                               unsigned short* __restrict__ outB) {
  __shared__ unsigned short As[32 * 32];
  __shared__ unsigned short Bs[128 * 32];
  const int tid = threadIdx.x;
  const int lane = tid & 63, wcq = tid >> 6;
  const int n0 = blockIdx.x * 128;
  f32x4 acc[2][2] = {};
  for (int kk = 0; kk < K; kk += 32) {
    uint4 av, bv0, bv1;
    if (tid < 128) {
      int row = tid >> 2, c8 = (tid & 3) * 8;
      av = *(const uint4*)(A + (size_t)row * K + kk + c8);
    }
    {
      int c = tid * 2, row = c >> 2, c8 = (c & 3) * 8;
      bv0 = *(const uint4*)(BT + (size_t)(n0 + row) * K + kk + c8);
      c = tid * 2 + 1; row = c >> 2; c8 = (c & 3) * 8;
      bv1 = *(const uint4*)(BT + (size_t)(n0 + row) * K + kk + c8);
    }
    __syncthreads();
    if (tid < 128) ((uint4*)As)[tid] = av;
    ((uint4*)Bs)[tid * 2] = bv0;
    ((uint4*)Bs)[tid * 2 + 1] = bv1;
    __syncthreads();
    short8 a0 = *(const short8*)(As + ((lane & 15)) * 32 + (lane >> 4) * 8);
    short8 a1 = *(const short8*)(As + (16 + (lane & 15)) * 32 + (lane >> 4) * 8);
    short8 b0 = *(const short8*)(Bs + (wcq * 32 + (lane & 15)) * 32 + (lane >> 4) * 8);
    short8 b1 = *(const short8*)(Bs + (wcq * 32 + 16 + (lane & 15)) * 32 + (lane >> 4) * 8);
    acc[0][0] = __builtin_amdgcn_mfma_f32_16x16x32_bf16(a0, b0, acc[0][0], 0, 0, 0);
    acc[0][1] = __builtin_amdgcn_mfma_f32_16x16x32_bf16(a0, b1, acc[0][1], 0, 0, 0);
    acc[1][0] = __builtin_amdgcn_mfma_f32_16x16x32_bf16(a1, b0, acc[1][0], 0, 0, 0);
    acc[1][1] = __builtin_amdgcn_mfma_f32_16x16x32_bf16(a1, b1, acc[1][1], 0, 0, 0);
  }
#pragma unroll
  for (int m = 0; m < 2; ++m)
#pragma unroll
    for (int n = 0; n < 2; ++n)
#pragma unroll
      for (int reg = 0; reg < 4; ++reg) {
        int r = m * 16 + (lane >> 4) * 4 + reg;
        int c = n0 + wcq * 32 + n * 16 + (lane & 15);
        float v = acc[m][n][reg];
        if (MODE == 0) outF[(size_t)r * N + c] = v + bias[c];
        else outB[(size_t)r * N + c] = f2bf(ftanh(v));
      }
}

// --------------------------- per-step kernels ------------------------------

// GRU gates: h_new = (1-z)*n + z*h ; writes h_row (fp32) and h_bf (bf16) in place
__global__ __launch_bounds__(256) void k_gates(const unsigned short* __restrict__ gi_t,
                                               const float* __restrict__ ghf,
                                               float* __restrict__ h_row,
                                               unsigned short* __restrict__ h_bf) {
  int idx = blockIdx.x * 256 + threadIdx.x;  // 16384
  int b = idx >> 9, j = idx & 511;
  size_t gb = (size_t)b * 1536;
  float ir = bf2f(gi_t[gb + j]);
  float iz = bf2f(gi_t[gb + 512 + j]);
  float in_ = bf2f(gi_t[gb + 1024 + j]);
  float hr = ghf[gb + j];
  float hz = ghf[gb + 512 + j];
  float hn = ghf[gb + 1024 + j];
  float r = fsigmoid(ir + hr);
  float z = fsigmoid(iz + hz);
  float n = ftanh(in_ + r * hn);
  float hp = h_row[b * 512 + j];
  float hv = (1.f - z) * n + z * hp;
  h_row[b * 512 + j] = hv;
  h_bf[b * 512 + j] = f2bf(hv);
}

// encoder attention scores: one wave per (b,s); sc = tanh(qc+pkc)@we_c + be_c, masked
__global__ __launch_bounds__(256) void k_score_c(const unsigned short* __restrict__ pkc,
                                                 const float* __restrict__ qcqu,
                                                 const float* __restrict__ we_c,
                                                 const float* __restrict__ be_c,
                                                 const int* __restrict__ src_mask,
                                                 float* __restrict__ sc) {
  int w = threadIdx.x >> 6, lane = threadIdx.x & 63;
  int pair = blockIdx.x * 4 + w;  // b*400+s
  int b = pair / 400;
  int d0 = lane * 8;
  const float* qb = qcqu + b * 1024 + d0;
  float4 q0 = *(const float4*)qb;
  float4 q1 = *(const float4*)(qb + 4);
  float4 w0 = *(const float4*)(we_c + d0);
  float4 w1 = *(const float4*)(we_c + d0 + 4);
  uint4 pk = *(const uint4*)(pkc + (size_t)pair * 512 + d0);
  float acc =
      ftanh(q0.x + bf2f((unsigned short)(pk.x & 0xffff))) * w0.x +
      ftanh(q0.y + bf2f((unsigned short)(pk.x >> 16))) * w0.y +
      ftanh(q0.z + bf2f((unsigned short)(pk.y & 0xffff))) * w0.z +
      ftanh(q0.w + bf2f((unsigned short)(pk.y >> 16))) * w0.w +
      ftanh(q1.x + bf2f((unsigned short)(pk.z & 0xffff))) * w1.x +
      ftanh(q1.y + bf2f((unsigned short)(pk.z >> 16))) * w1.y +
      ftanh(q1.z + bf2f((unsigned short)(pk.w & 0xffff))) * w1.z +
      ftanh(q1.w + bf2f((unsigned short)(pk.w >> 16))) * w1.w;
#pragma unroll
  for (int m = 1; m < 64; m <<= 1) acc += __shfl_xor(acc, m, 64);
  if (lane == 0) {
    float v = acc + be_c[0];
    sc[pair] = (src_mask[pair] != 0) ? v : -1e9f;
  }
}

// softmax over S=400 + ctx_c: grid = 32 b * 4 chunks of 256 dims
__global__ __launch_bounds__(256) void k_softctx_c(const float* __restrict__ sc,
                                                   const unsigned short* __restrict__ encb,
                                                   float* __restrict__ ctxc) {
  int b = blockIdx.x >> 2, chunk = blockIdx.x & 3;
  int t = threadIdx.x;
  __shared__ float red[256];
  __shared__ float ac[512];
  float v0 = (t < 400) ? sc[b * 400 + t] : -3e38f;
  float v1 = (t + 256 < 400) ? sc[b * 400 + t + 256] : -3e38f;
  red[t] = fmaxf(v0, v1);
  __syncthreads();
  for (int s = 128; s > 0; s >>= 1) {
    if (t < s) red[t] = fmaxf(red[t], red[t + s]);
    __syncthreads();
  }
  float smax = red[0];
  __syncthreads();
  float e0 = (t < 400) ? __expf(v0 - smax) : 0.f;
  float e1 = (t + 256 < 400) ? __expf(v1 - smax) : 0.f;
  ac[t] = e0; ac[t + 256] = e1;
  red[t] = e0 + e1;
  __syncthreads();
  for (int s = 128; s > 0; s >>= 1) {
    if (t < s) red[t] += red[t + s];
    __syncthreads();
  }
  float denom = red[0];
  int d = chunk * 256 + t;
  const unsigned short* ep = encb + (size_t)b * 400 * 1024 + d;
  float acc = 0.f;
#pragma unroll 4
  for (int s = 0; s < 400; ++s) acc += ac[s] * bf2f(ep[(size_t)s * 1024]);
  ctxc[b * 1024 + d] = acc / denom;
}

// user attention + copy gate + cat assembly: one block per b
__global__ __launch_bounds__(256) void k_attn_u(const unsigned short* __restrict__ pku,
                                                const float* __restrict__ qcqu,
                                                const float* __restrict__ we_u,
                                                const float* __restrict__ be_u,
                                                const unsigned short* __restrict__ uve,
                                                const float* __restrict__ Wg,
                                                const float* __restrict__ bg,
                                                const float* __restrict__ ctxc,
                                                const unsigned short* __restrict__ h_bf,
                                                const float* __restrict__ user_embed,
                                                unsigned short* __restrict__ cat_bf,
                                                float* __restrict__ au_out,
                                                float* __restrict__ cp_out) {
  int b = blockIdx.x;
  int t = threadIdx.x;
  int w = t >> 6, lane = t & 63;
  __shared__ float su[256];
  __shared__ float red[256];
  __shared__ float cu[300];
  int d0 = lane * 8;
  const float* qb = qcqu + b * 1024 + 512 + d0;
  float4 q0 = *(const float4*)qb;
  float4 q1 = *(const float4*)(qb + 4);
  float4 w0 = *(const float4*)(we_u + d0);
  float4 w1 = *(const float4*)(we_u + d0 + 4);
  for (int i = 0; i < 50; ++i) {
    int v = w * 50 + i;
    uint4 pk = *(const uint4*)(pku + (size_t)(b * 200 + v) * 512 + d0);
    float acc =
        ftanh(q0.x + bf2f((unsigned short)(pk.x & 0xffff))) * w0.x +
        ftanh(q0.y + bf2f((unsigned short)(pk.x >> 16))) * w0.y +
        ftanh(q0.z + bf2f((unsigned short)(pk.y & 0xffff))) * w0.z +
        ftanh(q0.w + bf2f((unsigned short)(pk.y >> 16))) * w0.w +
        ftanh(q1.x + bf2f((unsigned short)(pk.z & 0xffff))) * w1.x +
        ftanh(q1.y + bf2f((unsigned short)(pk.z >> 16))) * w1.y +
        ftanh(q1.z + bf2f((unsigned short)(pk.w & 0xffff))) * w1.z +
        ftanh(q1.w + bf2f((unsigned short)(pk.w >> 16))) * w1.w;
#pragma unroll
    for (int m = 1; m < 64; m <<= 1) acc += __shfl_xor(acc, m, 64);
    if (lane == 0) su[v] = acc + be_u[0];
  }
  __syncthreads();
  // softmax over 200
  float sv = (t < 200) ? su[t] : -3e38f;
  red[t] = sv;
  __syncthreads();
  for (int s = 128; s > 0; s >>= 1) {
    if (t < s) red[t] = fmaxf(red[t], red[t + s]);
    __syncthreads();
  }
  float smax = red[0];
  __syncthreads();
  float e = (t < 200) ? __expf(sv - smax) : 0.f;
  red[t] = e;
  __syncthreads();
  for (int s = 128; s > 0; s >>= 1) {
    if (t < s) red[t] += red[t + s];
    __syncthreads();
  }
  float denom = red[0];
  float a = e / denom;
  __syncthreads();
  if (t < 200) {
    su[t] = a;
    au_out[b * 200 + t] = a;
  }
  __syncthreads();
  // ctx_u
  for (int ee = t; ee < 300; ee += 256) {
    const unsigned short* up = uve + (size_t)(b * 200) * 320 + ee;
    float acc = 0.f;
#pragma unroll 4
    for (int v = 0; v < 200; ++v) acc += su[v] * bf2f(up[(size_t)v * 320]);
    cu[ee] = acc;
  }
  __syncthreads();
  // cat = [q(512), ctx_c(1024), ctx_u(300), user_embed(300), pad(8)]
  for (int i = t; i < 2144; i += 256) {
    unsigned short ov;
    if (i < 512) ov = h_bf[b * 512 + i];
    else if (i < 1536) ov = f2bf(ctxc[b * 1024 + (i - 512)]);
    else if (i < 1836) ov = f2bf(cu[i - 1536]);
    else if (i < 2136) ov = f2bf(user_embed[b * 300 + (i - 1836)]);
    else ov = 0;
    cat_bf[b * 2144 + i] = ov;
  }
  // copy gate: sigmoid([ctx_c, q, ctx_u] @ Wg + bg)
  float p = 0.f;
  for (int k = t; k < 1836; k += 256) {
    float val;
    if (k < 1024) val = ctxc[b * 1024 + k];
    else if (k < 1536) val = bf2f(h_bf[b * 512 + (k - 1024)]);
    else val = cu[k - 1536];
    p += val * Wg[k];
  }
  red[t] = p;
  __syncthreads();
  for (int s = 128; s > 0; s >>= 1) {
    if (t < s) red[t] += red[t + s];
    __syncthreads();
  }
  if (t == 0) cp_out[b] = fsigmoid(red[0] + bg[0]);
}

// finalize: scale by (1-cp)/rowsum, zero pad cols, scatter-add copy probs
__global__ __launch_bounds__(256) void k_finalize(float* __restrict__ out,
                                                  const float* __restrict__ rowsum,
                                                  const float* __restrict__ cp_all,
                                                  const float* __restrict__ au_all,
                                                  const int* __restrict__ sv) {
  int r = blockIdx.x;  // t*32+b
  int t = threadIdx.x;
  int b = r & 31, tt = r >> 5;
  float cp = cp_all[r];
  float scale = (1.f - cp) / rowsum[r];
  float* base = out + (size_t)(b * 32 + tt) * 50200;
  float4* b4 = (float4*)base;
  for (int i = t; i < 12550; i += 256) {
    if (i < 12500) {
      float4 v = b4[i];
      v.x *= scale; v.y *= scale; v.z *= scale; v.w *= scale;
      b4[i] = v;
    } else {
      b4[i] = make_float4(0.f, 0.f, 0.f, 0.f);
    }
  }
  __syncthreads();
  if (t < 200) {
    int idx = sv[b * 200 + t];
    atomicAdd(base + idx, cp * au_all[(size_t)r * 200 + t]);
  }
}

// ---------------------------------------------------------------------------

extern "C" void kernel_launch(void* const* d_in, const int* in_sizes, int n_in,
                              void* d_out, int out_size, void* d_ws, size_t ws_size,
                              hipStream_t stream) {
  (void)in_sizes; (void)n_in; (void)out_size; (void)ws_size;
  const float* enc = (const float*)d_in[0];
  const float* hidden0 = (const float*)d_in[1];
  const float* user_embed = (const float*)d_in[2];
  const float* W_embed = (const float*)d_in[3];
  const float* W_ih = (const float*)d_in[4];
  const float* W_hh = (const float*)d_in[5];
  const float* b_ih = (const float*)d_in[6];
  const float* b_hh = (const float*)d_in[7];
  const float* Wk_c = (const float*)d_in[8];
  const float* bk_c = (const float*)d_in[9];
  const float* Wq_c = (const float*)d_in[10];
  const float* bq_c = (const float*)d_in[11];
  const float* we_c = (const float*)d_in[12];
  const float* be_c = (const float*)d_in[13];
  const float* Wk_u = (const float*)d_in[14];
  const float* bk_u = (const float*)d_in[15];
  const float* Wq_u = (const float*)d_in[16];
  const float* bq_u = (const float*)d_in[17];
  const float* we_u = (const float*)d_in[18];
  const float* be_u = (const float*)d_in[19];
  const float* Wc = (const float*)d_in[20];
  const float* Wg = (const float*)d_in[21];
  const float* bg = (const float*)d_in[22];
  const float* Wgen = (const float*)d_in[23];
  const int* src_mask = (const int*)d_in[24];
  const int* tgt = (const int*)d_in[25];
  const int* sv = (const int*)d_in[26];
  float* out = (float*)d_out;

  // workspace layout (~115 MB)
  char* w = (char*)d_ws;
  auto alloc = [&](size_t bytes) {
    void* p = (void*)w;
    w += (bytes + 255) & ~(size_t)255;
    return p;
  };
  unsigned short* WT = (unsigned short*)alloc(50000ull * 512 * 2);     // Wgen^T bf16
  unsigned short* encb = (unsigned short*)alloc(12800ull * 1024 * 2);  // enc bf16
  unsigned short* pkc = (unsigned short*)alloc(12800ull * 512 * 2);
  unsigned short* uve = (unsigned short*)alloc(6400ull * 320 * 2);
  unsigned short* pku = (unsigned short*)alloc(6400ull * 512 * 2);
  unsigned short* WkcT = (unsigned short*)alloc(512ull * 1024 * 2);
  unsigned short* WkuT = (unsigned short*)alloc(512ull * 320 * 2);
  unsigned short* WqcuT = (unsigned short*)alloc(1024ull * 512 * 2);
  unsigned short* WcT = (unsigned short*)alloc(512ull * 2144 * 2);
  unsigned short* WihT = (unsigned short*)alloc(1536ull * 320 * 2);
  unsigned short* Whhb = (unsigned short*)alloc(1536ull * 512 * 2);
  unsigned short* xe = (unsigned short*)alloc(1024ull * 320 * 2);
  unsigned short* gib = (unsigned short*)alloc(1024ull * 1536 * 2);
  unsigned short* chb = (unsigned short*)alloc(1024ull * 512 * 2);
  float* h_row = (float*)alloc(32ull * 512 * 4);
  unsigned short* h_bf = (unsigned short*)alloc(32ull * 512 * 2);
  float* ghf = (float*)alloc(32ull * 1536 * 4);
  float* qcqu = (float*)alloc(32ull * 1024 * 4);
  float* scb = (float*)alloc(12800ull * 4);
  float* ctxc = (float*)alloc(32ull * 1024 * 4);
  unsigned short* catb = (unsigned short*)alloc(32ull * 2144 * 2);
  float* aual = (float*)alloc(1024ull * 200 * 4);
  float* cpal = (float*)alloc(1024ull * 4);
  float* rsum = (float*)alloc(1024ull * 4);
  float* bqcu = (float*)alloc(1024ull * 4);

  // ---------------- precompute ----------------
  hipMemcpyAsync(h_row, hidden0, 32 * 512 * 4, hipMemcpyDeviceToDevice, stream);
  hipMemcpyAsync(bqcu, bq_c, 512 * 4, hipMemcpyDeviceToDevice, stream);
  hipMemcpyAsync(bqcu + 512, bq_u, 512 * 4, hipMemcpyDeviceToDevice, stream);
  hipMemsetAsync(rsum, 0, 1024 * 4, stream);

  k_cast_f2b<<<16, 256, 0, stream>>>(hidden0, h_bf, 4096);
  k_cast_f2b<<<2048, 256, 0, stream>>>(enc, encb, 3276800);
  k_cast_f2b<<<768, 256, 0, stream>>>(W_hh, Whhb, 196608);
  k_tcast<<<dim3(1563, 16), 256, 0, stream>>>(Wgen, WT, 512, 50000, 512);
  k_tcast<<<dim3(16, 32), 256, 0, stream>>>(Wk_c, WkcT, 1024, 512, 1024);
  k_tcast<<<dim3(16, 10), 256, 0, stream>>>(Wk_u, WkuT, 300, 512, 320);
  k_tcast<<<dim3(16, 16), 256, 0, stream>>>(Wq_c, WqcuT, 512, 512, 512);
  k_tcast<<<dim3(16, 16), 256, 0, stream>>>(Wq_u, WqcuT + 512ull * 512, 512, 512, 512);
  k_tcast<<<dim3(16, 67), 256, 0, stream>>>(Wc, WcT, 2136, 512, 2144);
  k_castpad<<<1536, 64, 0, stream>>>(W_ih, WihT, 300, 320);
  k_gather_xe<<<1024, 64, 0, stream>>>(W_embed, tgt, xe);
  k_gather_uve<<<6400, 64, 0, stream>>>(W_embed, sv, uve);

  // proj_key_c = enc @ Wk_c + bk_c   [12800 x 512], bf16
  gemm_bt<0><<<200, 512, 0, stream>>>(encb, WkcT, 12800, 512, 1024, 4, bk_c, pkc, nullptr, nullptr);
  // proj_key_u = uve @ Wk_u + bk_u   [6400 x 512], bf16
  gemm_bt<0><<<100, 512, 0, stream>>>(uve, WkuT, 6400, 512, 320, 4, bk_u, pku, nullptr, nullptr);
  // gi_all = x @ W_ih.T + b_ih       [1024 x 1536], bf16
  gemm_bt<0><<<48, 512, 0, stream>>>(xe, WihT, 1024, 1536, 320, 12, b_ih, gib, nullptr, nullptr);

  // ---------------- sequential steps ----------------
  for (int t = 0; t < 32; ++t) {
    // gh = h @ W_hh.T + b_hh
    gemm_ms<0><<<12, 256, 0, stream>>>(h_bf, Whhb, 1536, 512, b_hh, ghf, nullptr);
    k_gates<<<64, 256, 0, stream>>>(gib + (size_t)t * 32 * 1536, ghf, h_row, h_bf);
    // [qc | qu] = h @ [Wq_c | Wq_u] + [bq_c | bq_u]
    gemm_ms<0><<<8, 256, 0, stream>>>(h_bf, WqcuT, 1024, 512, bqcu, qcqu, nullptr);
    k_score_c<<<3200, 256, 0, stream>>>(pkc, qcqu, we_c, be_c, src_mask, scb);
    k_softctx_c<<<128, 256, 0, stream>>>(scb, encb, ctxc);
    k_attn_u<<<32, 256, 0, stream>>>(pku, qcqu, we_u, be_u, uve, Wg, bg, ctxc, h_bf,
                                     user_embed, catb, aual + (size_t)t * 32 * 200,
                                     cpal + t * 32);
    // ch = tanh(cat @ Wc) -> bf16 rows of A for the vocab GEMM
    gemm_ms<1><<<4, 256, 0, stream>>>(catb, WcT, 512, 2144, nullptr, nullptr,
                                      chb + (size_t)t * 32 * 512);
  }

  // ---------------- vocab GEMM + softmax + mix ----------------
  gemm_bt<1><<<4 * 391, 512, 0, stream>>>(chb, WT, 1024, 50000, 512, 391, nullptr,
                                          nullptr, out, rsum);
  k_finalize<<<1024, 256, 0, stream>>>(out, rsum, cpal, aual, sv);
}

// Round 2
// 4472.051 us; speedup vs baseline: 1.2873x; 1.2873x over previous
//
#include <hip/hip_runtime.h>
#include <hip/hip_cooperative_groups.h>

namespace cg = cooperative_groups;

// ---------------------------------------------------------------------------
// Pointer-generator decoder. B=32 S=400 H=512 E=300 Vs=200 T=32 EN=50000 V=50200
// Round 2: persistent cooperative kernel for the 32-step loop (3 grid syncs
// per step), batched ch-GEMM after the loop, deferred vocab GEMM + finalize.
// ---------------------------------------------------------------------------

typedef __attribute__((ext_vector_type(8))) short short8;
typedef __attribute__((ext_vector_type(4))) float f32x4;

__device__ __forceinline__ float bf2f(unsigned short u) {
  return __uint_as_float(((unsigned)u) << 16);
}
__device__ __forceinline__ unsigned short f2bf(float f) {
  unsigned x = __float_as_uint(f);
  unsigned r = x + 0x7fffu + ((x >> 16) & 1u);
  return (unsigned short)(r >> 16);
}
__device__ __forceinline__ float fsigmoid(float x) { return 1.f / (1.f + __expf(-x)); }
__device__ __forceinline__ float ftanh(float x) {
  float t = __expf(-2.f * fabsf(x));
  float r = (1.f - t) / (1.f + t);
  return x >= 0.f ? r : -r;
}
__device__ __forceinline__ float tanh_dot8(float4 q0, float4 q1, float4 w0, float4 w1,
                                           uint4 pk) {
  return ftanh(q0.x + bf2f((unsigned short)(pk.x & 0xffff))) * w0.x +
         ftanh(q0.y + bf2f((unsigned short)(pk.x >> 16))) * w0.y +
         ftanh(q0.z + bf2f((unsigned short)(pk.y & 0xffff))) * w0.z +
         ftanh(q0.w + bf2f((unsigned short)(pk.y >> 16))) * w0.w +
         ftanh(q1.x + bf2f((unsigned short)(pk.z & 0xffff))) * w1.x +
         ftanh(q1.y + bf2f((unsigned short)(pk.z >> 16))) * w1.y +
         ftanh(q1.z + bf2f((unsigned short)(pk.w & 0xffff))) * w1.z +
         ftanh(q1.w + bf2f((unsigned short)(pk.w >> 16))) * w1.w;
}

// --------------------------- precompute kernels ----------------------------

__global__ __launch_bounds__(256) void k_cast_f2b(const float* __restrict__ src,
                                                  unsigned short* __restrict__ dst,
                                                  int n4) {
  int stride = gridDim.x * blockDim.x;
  for (int i = blockIdx.x * blockDim.x + threadIdx.x; i < n4; i += stride) {
    float4 v = ((const float4*)src)[i];
    ushort4 o;
    o.x = f2bf(v.x); o.y = f2bf(v.y); o.z = f2bf(v.z); o.w = f2bf(v.w);
    ((ushort4*)dst)[i] = o;
  }
}

// transpose + cast: src [R][C] f32 -> dst [C][Rpad] bf16 (zero pad rows >= R)
__global__ __launch_bounds__(256) void k_tcast(const float* __restrict__ src,
                                               unsigned short* __restrict__ dst,
                                               int R, int C, int Rpad) {
  __shared__ float tile[32][33];
  int c0 = blockIdx.x * 32, r0 = blockIdx.y * 32;
  int tx = threadIdx.x & 31, ty = threadIdx.x >> 5;
#pragma unroll
  for (int i = 0; i < 4; ++i) {
    int r = r0 + ty + i * 8, c = c0 + tx;
    tile[ty + i * 8][tx] = (r < R && c < C) ? src[(size_t)r * C + c] : 0.f;
  }
  __syncthreads();
#pragma unroll
  for (int i = 0; i < 4; ++i) {
    int c = c0 + ty + i * 8, rr = r0 + tx;
    if (c < C && rr < Rpad) dst[(size_t)c * Rpad + rr] = f2bf(tile[tx][ty + i * 8]);
  }
}

__global__ __launch_bounds__(64) void k_castpad(const float* __restrict__ src,
                                                unsigned short* __restrict__ dst,
                                                int C, int Cpad) {
  int row = blockIdx.x;
  for (int k = threadIdx.x; k < Cpad; k += 64)
    dst[(size_t)row * Cpad + k] = (k < C) ? f2bf(src[(size_t)row * C + k]) : (unsigned short)0;
}

__global__ __launch_bounds__(64) void k_gather_xe(const float* __restrict__ W_embed,
                                                  const int* __restrict__ tgt,
                                                  unsigned short* __restrict__ xe) {
  int r = blockIdx.x;
  int t = r >> 5, b = r & 31;
  int tok = (t == 0) ? 1 : tgt[b * 32 + (t - 1)];
  const float* src = W_embed + (size_t)tok * 300;
  for (int k = threadIdx.x; k < 320; k += 64)
    xe[(size_t)r * 320 + k] = (k < 300) ? f2bf(src[k]) : (unsigned short)0;
}

__global__ __launch_bounds__(64) void k_gather_uve(const float* __restrict__ W_embed,
                                                   const int* __restrict__ sv,
                                                   unsigned short* __restrict__ uve) {
  int row = blockIdx.x;  // b*200+v
  int tok = sv[row];
  const float* src = W_embed + (size_t)tok * 300;
  for (int k = threadIdx.x; k < 320; k += 64)
    uve[(size_t)row * 320 + k] = (k < 300) ? f2bf(src[k]) : (unsigned short)0;
}

// prefill catall user_embed columns + pad, init gate_acc to bg, rsum to 0
__global__ __launch_bounds__(64) void k_prefill(const float* __restrict__ ue,
                                                const float* __restrict__ bg,
                                                unsigned short* __restrict__ catall,
                                                float* __restrict__ gate_acc,
                                                float* __restrict__ rsum) {
  int r = blockIdx.x;  // t*32+b
  int b = r & 31;
  unsigned short* row = catall + (size_t)r * 2144;
  for (int k = threadIdx.x; k < 308; k += 64)
    row[1836 + k] = (k < 300) ? f2bf(ue[b * 300 + k]) : (unsigned short)0;
  if (threadIdx.x == 0) { gate_acc[r] = bg[0]; rsum[r] = 0.f; }
}

// --------------------------- big MFMA GEMM ---------------------------------
// A [M][K] bf16, BT [N][K] bf16, BM=256 BN=128 BK=32, 512 threads.
// MODE 0: out bf16 = A@B + bias   MODE 2: out bf16 = tanh(A@B)
// MODE 1: out fp32 exp(logit) -> out[(r&31)*32+(r>>5)][c] of [1024][50200], rowsum atomics
template <int MODE>
__global__ __launch_bounds__(512) void gemm_bt(const unsigned short* __restrict__ A,
                                               const unsigned short* __restrict__ BT,
                                               int M, int N, int K, int Ntiles,
                                               const float* __restrict__ bias,
                                               unsigned short* __restrict__ outB,
                                               float* __restrict__ outF,
                                               float* __restrict__ rowsum) {
  __shared__ unsigned short As[256 * 32];
  __shared__ unsigned short Bs[128 * 32];
  __shared__ float rs[256];
  const int tid = threadIdx.x;
  const int lane = tid & 63, wid = tid >> 6;
  const int wr = wid >> 1, wc = wid & 1;
  const int bx = blockIdx.x;
  const int mt = bx / Ntiles, nt = bx - mt * Ntiles;
  const int m0 = mt * 256, n0 = nt * 128;
  f32x4 acc[4][4] = {};
  for (int kk = 0; kk < K; kk += 32) {
    uint4 av0, av1, bv;
    {
      int c = tid, row = c >> 2, c8 = (c & 3) * 8;
      av0 = *(const uint4*)(A + (size_t)(m0 + row) * K + kk + c8);
      c = tid + 512; row = c >> 2; c8 = (c & 3) * 8;
      av1 = *(const uint4*)(A + (size_t)(m0 + row) * K + kk + c8);
      c = tid; row = c >> 2; c8 = (c & 3) * 8;
      int nr = n0 + row; if (nr > N - 1) nr = N - 1;
      bv = *(const uint4*)(BT + (size_t)nr * K + kk + c8);
    }
    __syncthreads();
    ((uint4*)As)[tid] = av0;
    ((uint4*)As)[tid + 512] = av1;
    ((uint4*)Bs)[tid] = bv;
    __syncthreads();
    short8 af[4], bfr[4];
#pragma unroll
    for (int m = 0; m < 4; ++m)
      af[m] = *(const short8*)(As + (wr * 64 + m * 16 + (lane & 15)) * 32 + (lane >> 4) * 8);
#pragma unroll
    for (int n = 0; n < 4; ++n)
      bfr[n] = *(const short8*)(Bs + (wc * 64 + n * 16 + (lane & 15)) * 32 + (lane >> 4) * 8);
#pragma unroll
    for (int m = 0; m < 4; ++m)
#pragma unroll
      for (int n = 0; n < 4; ++n)
        acc[m][n] = __builtin_amdgcn_mfma_f32_16x16x32_bf16(af[m], bfr[n], acc[m][n], 0, 0, 0);
  }
  if (MODE == 0 || MODE == 2) {
#pragma unroll
    for (int m = 0; m < 4; ++m)
#pragma unroll
      for (int n = 0; n < 4; ++n)
#pragma unroll
        for (int reg = 0; reg < 4; ++reg) {
          int r = m0 + wr * 64 + m * 16 + (lane >> 4) * 4 + reg;
          int c = n0 + wc * 64 + n * 16 + (lane & 15);
          float v = acc[m][n][reg];
          if (MODE == 0) v += bias[c];
          else v = ftanh(v);
          outB[(size_t)r * N + c] = f2bf(v);
        }
  } else {
    if (tid < 256) rs[tid] = 0.f;
    __syncthreads();
#pragma unroll
    for (int m = 0; m < 4; ++m) {
#pragma unroll
      for (int reg = 0; reg < 4; ++reg) {
        int rloc = wr * 64 + m * 16 + (lane >> 4) * 4 + reg;
        int r = m0 + rloc;
        size_t obase = (size_t)((r & 31) * 32 + (r >> 5)) * 50200;
        float s = 0.f;
#pragma unroll
        for (int n = 0; n < 4; ++n) {
          int c = n0 + wc * 64 + n * 16 + (lane & 15);
          if (c < N) {
            float e = __expf(acc[m][n][reg]);
            outF[obase + c] = e;
            s += e;
          }
        }
        s += __shfl_xor(s, 1, 64); s += __shfl_xor(s, 2, 64);
        s += __shfl_xor(s, 4, 64); s += __shfl_xor(s, 8, 64);
        if ((lane & 15) == 0) atomicAdd(&rs[rloc], s);
      }
    }
    __syncthreads();
    if (tid < 256) atomicAdd(&rowsum[m0 + tid], rs[tid]);
  }
}

// --------------------------- persistent step kernel ------------------------

struct SP {
  const unsigned short *gib, *Whhb, *WqcuT, *pkc, *pku, *encb, *uve;
  const float *bhh, *bqcu, *wec, *bec, *weu, *beu, *Wg;
  const int *src_mask;
  float *hrow0, *hrow1, *qcqu, *scb, *sub, *gate_acc, *aual;
  unsigned short *hbf0, *hbf1, *catall;
};

__device__ __forceinline__ float blk_rsum(float v, float* r8, int tid) {
#pragma unroll
  for (int m = 1; m < 64; m <<= 1) v += __shfl_xor(v, m, 64);
  __syncthreads();
  if ((tid & 63) == 0) r8[tid >> 6] = v;
  __syncthreads();
  return r8[0] + r8[1] + r8[2] + r8[3] + r8[4] + r8[5] + r8[6] + r8[7];
}
__device__ __forceinline__ float blk_rmax(float v, float* r8, int tid) {
#pragma unroll
  for (int m = 1; m < 64; m <<= 1) v = fmaxf(v, __shfl_xor(v, m, 64));
  __syncthreads();
  if ((tid & 63) == 0) r8[tid >> 6] = v;
  __syncthreads();
  float a = fmaxf(fmaxf(r8[0], r8[1]), fmaxf(r8[2], r8[3]));
  float b = fmaxf(fmaxf(r8[4], r8[5]), fmaxf(r8[6], r8[7]));
  return fmaxf(a, b);
}

// P1: GRU (blocks 0..7, j-slice of 64). h_new = (1-z)*n + z*h
__device__ void phase1(const SP& P, int t, int bid, int tid,
                       unsigned short* As, unsigned short* Bs, float* ghs) {
  const int lane = tid & 63, w = tid >> 6;
  const int j0 = bid * 64;
  const int p = t & 1;
  const unsigned short* hb = p ? P.hbf1 : P.hbf0;
  const float* hr = p ? P.hrow1 : P.hrow0;
  unsigned short* hbn = p ? P.hbf0 : P.hbf1;
  float* hrn = p ? P.hrow0 : P.hrow1;
  f32x4 acc[3] = {};
  for (int kk = 0; kk < 512; kk += 32) {
    uint4 av = {0, 0, 0, 0}, bv1 = {0, 0, 0, 0};
    if (tid < 128) av = *(const uint4*)(hb + (tid >> 2) * 512 + kk + (tid & 3) * 8);
    int lr0 = tid >> 2, g0 = lr0 >> 6, jj0 = lr0 & 63;
    uint4 bv0 = *(const uint4*)(P.Whhb + (size_t)(g0 * 512 + j0 + jj0) * 512 + kk + (tid & 3) * 8);
    if (tid < 256) {
      int lr1 = (tid + 512) >> 2, g1 = lr1 >> 6, jj1 = lr1 & 63;
      bv1 = *(const uint4*)(P.Whhb + (size_t)(g1 * 512 + j0 + jj1) * 512 + kk + (tid & 3) * 8);
    }
    __syncthreads();
    if (tid < 128) ((uint4*)As)[tid] = av;
    ((uint4*)Bs)[tid] = bv0;
    if (tid < 256) ((uint4*)Bs)[tid + 512] = bv1;
    __syncthreads();
    short8 a0 = *(const short8*)(As + (lane & 15) * 32 + (lane >> 4) * 8);
    short8 a1 = *(const short8*)(As + (16 + (lane & 15)) * 32 + (lane >> 4) * 8);
#pragma unroll
    for (int q = 0; q < 3; ++q) {
      int idx = w * 3 + q;
      int mi = idx & 1, ni = idx >> 1;
      short8 bf_ = *(const short8*)(Bs + (ni * 16 + (lane & 15)) * 32 + (lane >> 4) * 8);
      acc[q] = __builtin_amdgcn_mfma_f32_16x16x32_bf16(mi ? a1 : a0, bf_, acc[q], 0, 0, 0);
    }
  }
  __syncthreads();
#pragma unroll
  for (int q = 0; q < 3; ++q) {
    int idx = w * 3 + q;
    int mi = idx & 1, ni = idx >> 1;
#pragma unroll
    for (int reg = 0; reg < 4; ++reg) {
      int r = mi * 16 + (lane >> 4) * 4 + reg;
      int cl = ni * 16 + (lane & 15);
      ghs[cl * 33 + r] = acc[q][reg];
    }
  }
  __syncthreads();
#pragma unroll
  for (int u = 0; u < 4; ++u) {
    int idx = tid + u * 512;  // 2048 = 64 j * 32 b
    int jj = idx >> 5, b = idx & 31;
    float rr = ghs[jj * 33 + b] + P.bhh[j0 + jj];
    float zz = ghs[(64 + jj) * 33 + b] + P.bhh[512 + j0 + jj];
    float nn = ghs[(128 + jj) * 33 + b] + P.bhh[1024 + j0 + jj];
    size_t gb = (size_t)(t * 32 + b) * 1536;
    float ir = bf2f(P.gib[gb + j0 + jj]);
    float iz = bf2f(P.gib[gb + 512 + j0 + jj]);
    float in_ = bf2f(P.gib[gb + 1024 + j0 + jj]);
    float r_ = fsigmoid(ir + rr), z_ = fsigmoid(iz + zz);
    float n_ = ftanh(in_ + r_ * nn);
    float hp = hr[b * 512 + j0 + jj];
    float hv = (1.f - z_) * n_ + z_ * hp;
    hrn[b * 512 + j0 + jj] = hv;
    hbn[b * 512 + j0 + jj] = f2bf(hv);
  }
}

// P2: qcqu GEMM (blocks 0..15), cat h-slice (16..17), gate h-part (18)
__device__ void phase2(const SP& P, int t, int bid, int tid,
                       unsigned short* As, unsigned short* Bs) {
  const int p = t & 1;
  const unsigned short* hbn = p ? P.hbf0 : P.hbf1;
  const float* hrn = p ? P.hrow0 : P.hrow1;
  if (bid < 16) {
    const int lane = tid & 63, w = tid >> 6;
    const int n0 = bid * 64;
    const int mi = w & 1, ni = w >> 1;
    f32x4 acc = {};
    for (int kk = 0; kk < 512; kk += 32) {
      uint4 av = {0, 0, 0, 0}, bv = {0, 0, 0, 0};
      if (tid < 128) av = *(const uint4*)(hbn + (tid >> 2) * 512 + kk + (tid & 3) * 8);
      if (tid < 256) bv = *(const uint4*)(P.WqcuT + (size_t)(n0 + (tid >> 2)) * 512 + kk + (tid & 3) * 8);
      __syncthreads();
      if (tid < 128) ((uint4*)As)[tid] = av;
      if (tid < 256) ((uint4*)Bs)[tid] = bv;
      __syncthreads();
      short8 af = *(const short8*)(As + (mi * 16 + (lane & 15)) * 32 + (lane >> 4) * 8);
      short8 bf_ = *(const short8*)(Bs + (ni * 16 + (lane & 15)) * 32 + (lane >> 4) * 8);
      acc = __builtin_amdgcn_mfma_f32_16x16x32_bf16(af, bf_, acc, 0, 0, 0);
    }
#pragma unroll
    for (int reg = 0; reg < 4; ++reg) {
      int r = mi * 16 + (lane >> 4) * 4 + reg;
      int c = n0 + ni * 16 + (lane & 15);
      P.qcqu[r * 1024 + c] = acc[reg] + P.bqcu[c];
    }
  } else if (bid < 18) {
#pragma unroll
    for (int u = 0; u < 16; ++u) {
      int idx = (bid - 16) * 8192 + u * 512 + tid;
      int b = idx >> 9, c = idx & 511;
      P.catall[(size_t)(t * 32 + b) * 2144 + c] = hbn[idx];
    }
  } else if (bid == 18) {
    const int lane = tid & 63, w = tid >> 6;
    for (int i = 0; i < 4; ++i) {
      int b = w * 4 + i;
      const float* hp = hrn + b * 512 + lane * 8;
      float4 h0 = *(const float4*)hp, h1 = *(const float4*)(hp + 4);
      const float* gp = P.Wg + 1024 + lane * 8;
      float4 g0 = *(const float4*)gp, g1 = *(const float4*)(gp + 4);
      float a = h0.x * g0.x + h0.y * g0.y + h0.z * g0.z + h0.w * g0.w +
                h1.x * g1.x + h1.y * g1.y + h1.z * g1.z + h1.w * g1.w;
#pragma unroll
      for (int m = 1; m < 64; m <<= 1) a += __shfl_xor(a, m, 64);
      if (lane == 0) atomicAdd(&P.gate_acc[t * 32 + b], a);
    }
  }
}

// P3: attention scores (all blocks; 19200 wave-tasks)
__device__ void phase3(const SP& P, int t, int bid, int tid) {
  const int lane = tid & 63;
  const int gw = bid * 8 + (tid >> 6);
  const int d0 = lane * 8;
  for (int task = gw; task < 19200; task += 2048) {
    float acc;
    if (task < 12800) {
      int b = task / 400;
      const float* qb = P.qcqu + b * 1024 + d0;
      float4 q0 = *(const float4*)qb, q1 = *(const float4*)(qb + 4);
      float4 w0 = *(const float4*)(P.wec + d0), w1 = *(const float4*)(P.wec + d0 + 4);
      uint4 pk = *(const uint4*)(P.pkc + (size_t)task * 512 + d0);
      acc = tanh_dot8(q0, q1, w0, w1, pk);
#pragma unroll
      for (int m = 1; m < 64; m <<= 1) acc += __shfl_xor(acc, m, 64);
      if (lane == 0)
        P.scb[task] = (P.src_mask[task] != 0) ? acc + P.bec[0] : -1e9f;
    } else {
      int j = task - 12800;
      int b = j / 200;
      const float* qb = P.qcqu + b * 1024 + 512 + d0;
      float4 q0 = *(const float4*)qb, q1 = *(const float4*)(qb + 4);
      float4 w0 = *(const float4*)(P.weu + d0), w1 = *(const float4*)(P.weu + d0 + 4);
      uint4 pk = *(const uint4*)(P.pku + (size_t)j * 512 + d0);
      acc = tanh_dot8(q0, q1, w0, w1, pk);
#pragma unroll
      for (int m = 1; m < 64; m <<= 1) acc += __shfl_xor(acc, m, 64);
      if (lane == 0) P.sub[j] = acc + P.beu[0];
    }
  }
}

// P4: softmaxes + ctx_c + ctx_u + cat slices + gate partials + au store
__device__ void phase4(const SP& P, int t, int bid, int tid,
                       float* red, float* r8, float* ac, float* suw) {
  const int b = bid >> 3, chunk = bid & 7;
  const int row = t * 32 + b;
  // encoder softmax (each block independently)
  float v = (tid < 400) ? P.scb[b * 400 + tid] : -3.0e38f;
  float smax = blk_rmax(v, r8, tid);
  float e = (tid < 400) ? __expf(v - smax) : 0.f;
  if (tid < 400) ac[tid] = e;
  float denom = blk_rsum(e, r8, tid);
  // ctx_c over this block's 128 dims (4-way split over s)
  {
    int dl = tid & 127, qh = tid >> 7;
    const unsigned short* ep = P.encb + ((size_t)b * 400 + qh * 100) * 1024 + chunk * 128 + dl;
    float a = 0.f;
#pragma unroll 4
    for (int s = 0; s < 100; ++s) a += ac[qh * 100 + s] * bf2f(ep[(size_t)s * 1024]);
    red[tid] = a;
    __syncthreads();
    float gp = 0.f;
    if (tid < 128) {
      float ctx = (red[tid] + red[tid + 128] + red[tid + 256] + red[tid + 384]) / denom;
      int c = chunk * 128 + tid;
      P.catall[(size_t)row * 2144 + 512 + c] = f2bf(ctx);
      gp = ctx * P.Wg[c];
    }
    float gtot = blk_rsum(gp, r8, tid);
    if (tid == 0) atomicAdd(&P.gate_acc[row], gtot);
  }
  if (chunk >= 4) {
    // user softmax + ctx_u (75 dims per block, 4-way split over v)
    float uv = (tid < 200) ? P.sub[b * 200 + tid] : -3.0e38f;
    float umax = blk_rmax(uv, r8, tid);
    float ue = (tid < 200) ? __expf(uv - umax) : 0.f;
    float uden = blk_rsum(ue, r8, tid);
    if (tid < 200) suw[tid] = ue / uden;
    __syncthreads();
    if (chunk == 4 && tid < 200) P.aual[(size_t)row * 200 + tid] = suw[tid];
    int d0u = (chunk - 4) * 75;
    float a = 0.f;
    int dl = tid % 75, vh = tid / 75;
    if (tid < 300) {
      const unsigned short* up = P.uve + ((size_t)b * 200 + vh * 50) * 320 + d0u + dl;
#pragma unroll 4
      for (int vv = 0; vv < 50; ++vv) a += suw[vh * 50 + vv] * bf2f(up[(size_t)vv * 320]);
    }
    red[tid] = (tid < 300) ? a : 0.f;
    __syncthreads();
    float gp = 0.f;
    if (tid < 75) {
      float cu = red[tid] + red[tid + 75] + red[tid + 150] + red[tid + 225];
      int d = d0u + tid;
      P.catall[(size_t)row * 2144 + 1536 + d] = f2bf(cu);
      gp = cu * P.Wg[1536 + d];
    }
    float gtot = blk_rsum(gp, r8, tid);
    if (tid == 0) atomicAdd(&P.gate_acc[row], gtot);
  }
}

__global__ __launch_bounds__(512, 1) void k_step(SP P) {
  __shared__ unsigned short As[32 * 32];
  __shared__ unsigned short Bs[192 * 32];
  __shared__ float ghs[192 * 33];
  __shared__ float red[512];
  __shared__ float ac[400];
  __shared__ float suw[200];
  __shared__ float r8[8];
  cg::grid_group grid = cg::this_grid();
  const int bid = blockIdx.x, tid = threadIdx.x;
  for (int t = 0; t < 32; ++t) {
    if (t > 0) phase4(P, t - 1, bid, tid, red, r8, ac, suw);
    if (bid < 8) phase1(P, t, bid, tid, As, Bs, ghs);
    grid.sync();
    phase2(P, t, bid, tid, As, Bs);
    grid.sync();
    phase3(P, t, bid, tid);
    grid.sync();
  }
  phase4(P, 31, bid, tid, red, r8, ac, suw);
}

// finalize: cp = sigmoid(gate_acc); scale by (1-cp)/rowsum; zero pad; scatter cp*au
__global__ __launch_bounds__(256) void k_finalize(float* __restrict__ out,
                                                  const float* __restrict__ rowsum,
                                                  const float* __restrict__ gate_acc,
                                                  const float* __restrict__ au_all,
                                                  const int* __restrict__ sv) {
  int r = blockIdx.x;  // t*32+b
  int t = threadIdx.x;
  int b = r & 31, tt = r >> 5;
  float cp = fsigmoid(gate_acc[r]);
  float scale = (1.f - cp) / rowsum[r];
  float* base = out + (size_t)(b * 32 + tt) * 50200;
  float4* b4 = (float4*)base;
  for (int i = t; i < 12550; i += 256) {
    if (i < 12500) {
      float4 v = b4[i];
      v.x *= scale; v.y *= scale; v.z *= scale; v.w *= scale;
      b4[i] = v;
    } else {
      b4[i] = make_float4(0.f, 0.f, 0.f, 0.f);
    }
  }
  __syncthreads();
  if (t < 200) {
    int idx = sv[b * 200 + t];
    atomicAdd(base + idx, cp * au_all[(size_t)r * 200 + t]);
  }
}

// ---------------------------------------------------------------------------

extern "C" void kernel_launch(void* const* d_in, const int* in_sizes, int n_in,
                              void* d_out, int out_size, void* d_ws, size_t ws_size,
                              hipStream_t stream) {
  (void)in_sizes; (void)n_in; (void)out_size; (void)ws_size;
  const float* enc = (const float*)d_in[0];
  const float* hidden0 = (const float*)d_in[1];
  const float* user_embed = (const float*)d_in[2];
  const float* W_embed = (const float*)d_in[3];
  const float* W_ih = (const float*)d_in[4];
  const float* W_hh = (const float*)d_in[5];
  const float* b_ih = (const float*)d_in[6];
  const float* b_hh = (const float*)d_in[7];
  const float* Wk_c = (const float*)d_in[8];
  const float* bk_c = (const float*)d_in[9];
  const float* Wq_c = (const float*)d_in[10];
  const float* bq_c = (const float*)d_in[11];
  const float* we_c = (const float*)d_in[12];
  const float* be_c = (const float*)d_in[13];
  const float* Wk_u = (const float*)d_in[14];
  const float* bk_u = (const float*)d_in[15];
  const float* Wq_u = (const float*)d_in[16];
  const float* bq_u = (const float*)d_in[17];
  const float* we_u = (const float*)d_in[18];
  const float* be_u = (const float*)d_in[19];
  const float* Wc = (const float*)d_in[20];
  const float* Wg = (const float*)d_in[21];
  const float* bg = (const float*)d_in[22];
  const float* Wgen = (const float*)d_in[23];
  const int* src_mask = (const int*)d_in[24];
  const int* tgt = (const int*)d_in[25];
  const int* sv = (const int*)d_in[26];
  float* out = (float*)d_out;

  char* w = (char*)d_ws;
  auto alloc = [&](size_t bytes) {
    void* p = (void*)w;
    w += (bytes + 255) & ~(size_t)255;
    return p;
  };
  unsigned short* WT = (unsigned short*)alloc(50000ull * 512 * 2);
  unsigned short* encb = (unsigned short*)alloc(12800ull * 1024 * 2);
  unsigned short* pkc = (unsigned short*)alloc(12800ull * 512 * 2);
  unsigned short* uve = (unsigned short*)alloc(6400ull * 320 * 2);
  unsigned short* pku = (unsigned short*)alloc(6400ull * 512 * 2);
  unsigned short* WkcT = (unsigned short*)alloc(512ull * 1024 * 2);
  unsigned short* WkuT = (unsigned short*)alloc(512ull * 320 * 2);
  unsigned short* WqcuT = (unsigned short*)alloc(1024ull * 512 * 2);
  unsigned short* WcT = (unsigned short*)alloc(512ull * 2144 * 2);
  unsigned short* WihT = (unsigned short*)alloc(1536ull * 320 * 2);
  unsigned short* Whhb = (unsigned short*)alloc(1536ull * 512 * 2);
  unsigned short* xe = (unsigned short*)alloc(1024ull * 320 * 2);
  unsigned short* gib = (unsigned short*)alloc(1024ull * 1536 * 2);
  unsigned short* chb = (unsigned short*)alloc(1024ull * 512 * 2);
  unsigned short* catall = (unsigned short*)alloc(1024ull * 2144 * 2);
  unsigned short* hbf0 = (unsigned short*)alloc(32ull * 512 * 2);
  unsigned short* hbf1 = (unsigned short*)alloc(32ull * 512 * 2);
  float* hrow0 = (float*)alloc(32ull * 512 * 4);
  float* hrow1 = (float*)alloc(32ull * 512 * 4);
  float* qcqu = (float*)alloc(32ull * 1024 * 4);
  float* scb = (float*)alloc(12800ull * 4);
  float* sub = (float*)alloc(6400ull * 4);
  float* aual = (float*)alloc(1024ull * 200 * 4);
  float* gate_acc = (float*)alloc(1024ull * 4);
  float* rsum = (float*)alloc(1024ull * 4);
  float* bqcu = (float*)alloc(1024ull * 4);

  // ---------------- precompute ----------------
  hipMemcpyAsync(hrow0, hidden0, 32 * 512 * 4, hipMemcpyDeviceToDevice, stream);
  hipMemcpyAsync(bqcu, bq_c, 512 * 4, hipMemcpyDeviceToDevice, stream);
  hipMemcpyAsync(bqcu + 512, bq_u, 512 * 4, hipMemcpyDeviceToDevice, stream);

  k_cast_f2b<<<16, 256, 0, stream>>>(hidden0, hbf0, 4096);
  k_cast_f2b<<<2048, 256, 0, stream>>>(enc, encb, 3276800);
  k_cast_f2b<<<768, 256, 0, stream>>>(W_hh, Whhb, 196608);
  k_tcast<<<dim3(1563, 16), 256, 0, stream>>>(Wgen, WT, 512, 50000, 512);
  k_tcast<<<dim3(16, 32), 256, 0, stream>>>(Wk_c, WkcT, 1024, 512, 1024);
  k_tcast<<<dim3(16, 10), 256, 0, stream>>>(Wk_u, WkuT, 300, 512, 320);
  k_tcast<<<dim3(16, 16), 256, 0, stream>>>(Wq_c, WqcuT, 512, 512, 512);
  k_tcast<<<dim3(16, 16), 256, 0, stream>>>(Wq_u, WqcuT + 512ull * 512, 512, 512, 512);
  k_tcast<<<dim3(16, 67), 256, 0, stream>>>(Wc, WcT, 2136, 512, 2144);
  k_castpad<<<1536, 64, 0, stream>>>(W_ih, WihT, 300, 320);
  k_gather_xe<<<1024, 64, 0, stream>>>(W_embed, tgt, xe);
  k_gather_uve<<<6400, 64, 0, stream>>>(W_embed, sv, uve);
  k_prefill<<<1024, 64, 0, stream>>>(user_embed, bg, catall, gate_acc, rsum);

  gemm_bt<0><<<200, 512, 0, stream>>>(encb, WkcT, 12800, 512, 1024, 4, bk_c, pkc, nullptr, nullptr);
  gemm_bt<0><<<100, 512, 0, stream>>>(uve, WkuT, 6400, 512, 320, 4, bk_u, pku, nullptr, nullptr);
  gemm_bt<0><<<48, 512, 0, stream>>>(xe, WihT, 1024, 1536, 320, 12, b_ih, gib, nullptr, nullptr);

  // ---------------- persistent 32-step cooperative kernel ----------------
  SP sp;
  sp.gib = gib; sp.Whhb = Whhb; sp.WqcuT = WqcuT; sp.pkc = pkc; sp.pku = pku;
  sp.encb = encb; sp.uve = uve;
  sp.bhh = b_hh; sp.bqcu = bqcu; sp.wec = we_c; sp.bec = be_c;
  sp.weu = we_u; sp.beu = be_u; sp.Wg = Wg;
  sp.src_mask = src_mask;
  sp.hrow0 = hrow0; sp.hrow1 = hrow1; sp.qcqu = qcqu; sp.scb = scb; sp.sub = sub;
  sp.gate_acc = gate_acc; sp.aual = aual;
  sp.hbf0 = hbf0; sp.hbf1 = hbf1; sp.catall = catall;
  void* kargs[] = {(void*)&sp};
  hipLaunchCooperativeKernel((const void*)k_step, dim3(256), dim3(512), kargs, 0, stream);

  // ---------------- batched ch GEMM, vocab GEMM, finalize ----------------
  gemm_bt<2><<<16, 512, 0, stream>>>(catall, WcT, 1024, 512, 2144, 4, nullptr, chb,
                                     nullptr, nullptr);
  gemm_bt<1><<<4 * 391, 512, 0, stream>>>(chb, WT, 1024, 50000, 512, 391, nullptr,
                                          nullptr, out, rsum);
  k_finalize<<<1024, 256, 0, stream>>>(out, rsum, gate_acc, aual, sv);
}

// Round 3
// 1095.646 us; speedup vs baseline: 5.2542x; 4.0817x over previous
//
#include <hip/hip_runtime.h>
#include <hip/hip_cooperative_groups.h>

namespace cg = cooperative_groups;

// ---------------------------------------------------------------------------
// Pointer-generator decoder. B=32 S=400 H=512 E=300 Vs=200 T=32 EN=50000 V=50200
// Round 3: only the GRU is sequential (small cooperative kernel, 33 grid
// syncs); attention scores / softmax / contexts / gate / ch / vocab are all
// batched over the 32 steps as parallel kernels and MFMA GEMMs.
// ---------------------------------------------------------------------------

typedef __attribute__((ext_vector_type(8))) short short8;
typedef __attribute__((ext_vector_type(4))) float f32x4;
typedef unsigned short us;

__device__ __forceinline__ float bf2f(us u) {
  return __uint_as_float(((unsigned)u) << 16);
}
__device__ __forceinline__ us f2bf(float f) {
  unsigned x = __float_as_uint(f);
  unsigned r = x + 0x7fffu + ((x >> 16) & 1u);
  return (us)(r >> 16);
}
__device__ __forceinline__ float fsigmoid(float x) { return 1.f / (1.f + __expf(-x)); }
__device__ __forceinline__ float ftanh(float x) {
  float t = __expf(-2.f * fabsf(x));
  float r = (1.f - t) / (1.f + t);
  return x >= 0.f ? r : -r;
}

// --------------------------- precompute kernels ----------------------------

__global__ __launch_bounds__(256) void k_cast_f2b(const float* __restrict__ src,
                                                  us* __restrict__ dst, int n4) {
  int stride = gridDim.x * blockDim.x;
  for (int i = blockIdx.x * blockDim.x + threadIdx.x; i < n4; i += stride) {
    float4 v = ((const float4*)src)[i];
    ushort4 o;
    o.x = f2bf(v.x); o.y = f2bf(v.y); o.z = f2bf(v.z); o.w = f2bf(v.w);
    ((ushort4*)dst)[i] = o;
  }
}

// transpose + cast (f32 src): src [R][C] -> dst [C][Rpad] bf16, batched over z
__global__ __launch_bounds__(256) void k_tcastX(const float* __restrict__ src0,
                                                us* __restrict__ dst0,
                                                int R, int C, int Rpad,
                                                size_t srcB, size_t dstB) {
  __shared__ float tile[32][33];
  const float* src = src0 + (size_t)blockIdx.z * srcB;
  us* dst = dst0 + (size_t)blockIdx.z * dstB;
  int c0 = blockIdx.x * 32, r0 = blockIdx.y * 32;
  int tx = threadIdx.x & 31, ty = threadIdx.x >> 5;
#pragma unroll
  for (int i = 0; i < 4; ++i) {
    int r = r0 + ty + i * 8, c = c0 + tx;
    tile[ty + i * 8][tx] = (r < R && c < C) ? src[(size_t)r * C + c] : 0.f;
  }
  __syncthreads();
#pragma unroll
  for (int i = 0; i < 4; ++i) {
    int c = c0 + ty + i * 8, rr = r0 + tx;
    if (c < C && rr < Rpad) dst[(size_t)c * Rpad + rr] = f2bf(tile[tx][ty + i * 8]);
  }
}

// transpose (bf16 src): src [R][C] bf16 -> dst [C][Rpad] bf16, batched over z
__global__ __launch_bounds__(256) void k_tcastXb(const us* __restrict__ src0,
                                                 us* __restrict__ dst0,
                                                 int R, int C, int Rpad,
                                                 size_t srcB, size_t dstB) {
  __shared__ us tile[32][33];
  const us* src = src0 + (size_t)blockIdx.z * srcB;
  us* dst = dst0 + (size_t)blockIdx.z * dstB;
  int c0 = blockIdx.x * 32, r0 = blockIdx.y * 32;
  int tx = threadIdx.x & 31, ty = threadIdx.x >> 5;
#pragma unroll
  for (int i = 0; i < 4; ++i) {
    int r = r0 + ty + i * 8, c = c0 + tx;
    tile[ty + i * 8][tx] = (r < R && c < C) ? src[(size_t)r * C + c] : (us)0;
  }
  __syncthreads();
#pragma unroll
  for (int i = 0; i < 4; ++i) {
    int c = c0 + ty + i * 8, rr = r0 + tx;
    if (c < C && rr < Rpad) dst[(size_t)c * Rpad + rr] = tile[tx][ty + i * 8];
  }
}

__global__ __launch_bounds__(64) void k_castpad(const float* __restrict__ src,
                                                us* __restrict__ dst,
                                                int C, int Cpad) {
  int row = blockIdx.x;
  for (int k = threadIdx.x; k < Cpad; k += 64)
    dst[(size_t)row * Cpad + k] = (k < C) ? f2bf(src[(size_t)row * C + k]) : (us)0;
}

__global__ __launch_bounds__(64) void k_gather_xe(const float* __restrict__ W_embed,
                                                  const int* __restrict__ tgt,
                                                  us* __restrict__ xe) {
  int r = blockIdx.x;
  int t = r >> 5, b = r & 31;
  int tok = (t == 0) ? 1 : tgt[b * 32 + (t - 1)];
  const float* src = W_embed + (size_t)tok * 300;
  for (int k = threadIdx.x; k < 320; k += 64)
    xe[(size_t)r * 320 + k] = (k < 300) ? f2bf(src[k]) : (us)0;
}

__global__ __launch_bounds__(64) void k_gather_uve(const float* __restrict__ W_embed,
                                                   const int* __restrict__ sv,
                                                   us* __restrict__ uve) {
  int row = blockIdx.x;  // b*200+v
  int tok = sv[row];
  const float* src = W_embed + (size_t)tok * 300;
  for (int k = threadIdx.x; k < 320; k += 64)
    uve[(size_t)row * 320 + k] = (k < 300) ? f2bf(src[k]) : (us)0;
}

// pack Whh [1536][512] f32 into MFMA B-fragment order (bf16):
// F[((nt*16+kt)*64 + lane)*8 + i] = Whh[nt*16+(lane&15)][kt*32+(lane>>4)*8 + i]
__global__ __launch_bounds__(64) void k_fragpack(const float* __restrict__ W,
                                                 us* __restrict__ F) {
  int nt = blockIdx.x, kt = blockIdx.y, l = threadIdx.x;
  const float* src = W + (size_t)(nt * 16 + (l & 15)) * 512 + kt * 32 + (l >> 4) * 8;
  us* dst = F + ((size_t)(nt * 16 + kt) * 64 + l) * 8;
#pragma unroll
  for (int i = 0; i < 8; ++i) dst[i] = f2bf(src[i]);
}

// --------------------------- big MFMA GEMM ---------------------------------
// A [M][K] bf16, BT [N][K] bf16, BM=256 BN=128 BK=32, 512 threads.
// MODE 0: out bf16 = A@B + bias   MODE 2: out bf16 = tanh(A@B)
// MODE 1: out fp32 exp(logit) -> out[(r&31)*32+(r>>5)][c] of [1024][50200], rowsum atomics
template <int MODE>
__global__ __launch_bounds__(512) void gemm_bt(const us* __restrict__ A,
                                               const us* __restrict__ BT,
                                               int M, int N, int K, int Ntiles,
                                               const float* __restrict__ bias,
                                               us* __restrict__ outB,
                                               float* __restrict__ outF,
                                               float* __restrict__ rowsum) {
  __shared__ us As[256 * 32];
  __shared__ us Bs[128 * 32];
  __shared__ float rs[256];
  const int tid = threadIdx.x;
  const int lane = tid & 63, wid = tid >> 6;
  const int wr = wid >> 1, wc = wid & 1;
  const int bx = blockIdx.x;
  const int mt = bx / Ntiles, nt = bx - mt * Ntiles;
  const int m0 = mt * 256, n0 = nt * 128;
  f32x4 acc[4][4] = {};
  for (int kk = 0; kk < K; kk += 32) {
    uint4 av0, av1, bv;
    {
      int c = tid, row = c >> 2, c8 = (c & 3) * 8;
      av0 = *(const uint4*)(A + (size_t)(m0 + row) * K + kk + c8);
      c = tid + 512; row = c >> 2; c8 = (c & 3) * 8;
      av1 = *(const uint4*)(A + (size_t)(m0 + row) * K + kk + c8);
      c = tid; row = c >> 2; c8 = (c & 3) * 8;
      int nr = n0 + row; if (nr > N - 1) nr = N - 1;
      bv = *(const uint4*)(BT + (size_t)nr * K + kk + c8);
    }
    __syncthreads();
    ((uint4*)As)[tid] = av0;
    ((uint4*)As)[tid + 512] = av1;
    ((uint4*)Bs)[tid] = bv;
    __syncthreads();
    short8 af[4], bfr[4];
#pragma unroll
    for (int m = 0; m < 4; ++m)
      af[m] = *(const short8*)(As + (wr * 64 + m * 16 + (lane & 15)) * 32 + (lane >> 4) * 8);
#pragma unroll
    for (int n = 0; n < 4; ++n)
      bfr[n] = *(const short8*)(Bs + (wc * 64 + n * 16 + (lane & 15)) * 32 + (lane >> 4) * 8);
#pragma unroll
    for (int m = 0; m < 4; ++m)
#pragma unroll
      for (int n = 0; n < 4; ++n)
        acc[m][n] = __builtin_amdgcn_mfma_f32_16x16x32_bf16(af[m], bfr[n], acc[m][n], 0, 0, 0);
  }
  if (MODE == 0 || MODE == 2) {
#pragma unroll
    for (int m = 0; m < 4; ++m)
#pragma unroll
      for (int n = 0; n < 4; ++n)
#pragma unroll
        for (int reg = 0; reg < 4; ++reg) {
          int r = m0 + wr * 64 + m * 16 + (lane >> 4) * 4 + reg;
          int c = n0 + wc * 64 + n * 16 + (lane & 15);
          float v = acc[m][n][reg];
          if (MODE == 0) v += bias[c];
          else v = ftanh(v);
          outB[(size_t)r * N + c] = f2bf(v);
        }
  } else {
    if (tid < 256) rs[tid] = 0.f;
    __syncthreads();
#pragma unroll
    for (int m = 0; m < 4; ++m) {
#pragma unroll
      for (int reg = 0; reg < 4; ++reg) {
        int rloc = wr * 64 + m * 16 + (lane >> 4) * 4 + reg;
        int r = m0 + rloc;
        size_t obase = (size_t)((r & 31) * 32 + (r >> 5)) * 50200;
        float s = 0.f;
#pragma unroll
        for (int n = 0; n < 4; ++n) {
          int c = n0 + wc * 64 + n * 16 + (lane & 15);
          if (c < N) {
            float e = __expf(acc[m][n][reg]);
            outF[obase + c] = e;
            s += e;
          }
        }
        s += __shfl_xor(s, 1, 64); s += __shfl_xor(s, 2, 64);
        s += __shfl_xor(s, 4, 64); s += __shfl_xor(s, 8, 64);
        if ((lane & 15) == 0) atomicAdd(&rs[rloc], s);
      }
    }
    __syncthreads();
    if (tid < 256) atomicAdd(&rowsum[m0 + tid], rs[tid]);
  }
}

// --------------------------- GRU cooperative kernel ------------------------
// 32 blocks x 512 threads. Block bid owns j-tile bid (16 cols) of all 3 gates.
// Whh pre-packed in fragment order (L2-local per block). h in registers.
struct GP {
  const us* frag; const us* gib; const float* bhh; const float* hidden0;
  us* hball;   // [33][32][512] bf16: row0 = H_{-1}; row t+1 = H_t
  float* hfall; // [32][32][512] f32: H_t
};

__global__ __launch_bounds__(512, 1) void k_gru(GP P) {
  cg::grid_group grid = cg::this_grid();
  const int bid = blockIdx.x, tid = threadIdx.x;
  const int lane = tid & 63, w = tid >> 6;
  const int b_own = tid & 31, jj_own = tid >> 5;
  const int j_own = bid * 16 + jj_own;
  const int l_own = jj_own | (((b_own & 15) >> 2) << 4);
  const int r_own = b_own & 3;
  const int mt_own = b_own >> 4;
  __shared__ float part[8][3][2][64][4];  // 48KB
  float h_reg = P.hidden0[b_own * 512 + j_own];
  P.hball[b_own * 512 + j_own] = f2bf(h_reg);
  grid.sync();
  for (int t = 0; t < 32; ++t) {
    const us* hp = P.hball + (size_t)t * 16384;
    short8 af[2][2];
#pragma unroll
    for (int mt = 0; mt < 2; ++mt)
#pragma unroll
      for (int kq = 0; kq < 2; ++kq) {
        int kt = w * 2 + kq;
        af[mt][kq] = *(const short8*)(hp + (mt * 16 + (lane & 15)) * 512 + kt * 32 + (lane >> 4) * 8);
      }
    f32x4 acc[3][2] = {};
#pragma unroll
    for (int g = 0; g < 3; ++g) {
      int nt = g * 32 + bid;
#pragma unroll
      for (int kq = 0; kq < 2; ++kq) {
        int kt = w * 2 + kq;
        short8 bf_ = *(const short8*)(P.frag + ((size_t)(nt * 16 + kt) * 64 + lane) * 8);
#pragma unroll
        for (int mt = 0; mt < 2; ++mt)
          acc[g][mt] = __builtin_amdgcn_mfma_f32_16x16x32_bf16(af[mt][kq], bf_, acc[g][mt], 0, 0, 0);
      }
    }
#pragma unroll
    for (int g = 0; g < 3; ++g)
#pragma unroll
      for (int mt = 0; mt < 2; ++mt)
        *(f32x4*)&part[w][g][mt][lane][0] = acc[g][mt];
    __syncthreads();
    float gh0 = 0.f, gh1 = 0.f, gh2 = 0.f;
#pragma unroll
    for (int ww = 0; ww < 8; ++ww) {
      gh0 += part[ww][0][mt_own][l_own][r_own];
      gh1 += part[ww][1][mt_own][l_own][r_own];
      gh2 += part[ww][2][mt_own][l_own][r_own];
    }
    size_t gbase = (size_t)(t * 32 + b_own) * 1536;
    float r_ = fsigmoid(bf2f(P.gib[gbase + j_own]) + gh0 + P.bhh[j_own]);
    float z_ = fsigmoid(bf2f(P.gib[gbase + 512 + j_own]) + gh1 + P.bhh[512 + j_own]);
    float n_ = ftanh(bf2f(P.gib[gbase + 1024 + j_own]) + r_ * (gh2 + P.bhh[1024 + j_own]));
    h_reg = (1.f - z_) * n_ + z_ * h_reg;
    P.hball[(size_t)(t + 1) * 16384 + b_own * 512 + j_own] = f2bf(h_reg);
    P.hfall[(size_t)t * 16384 + b_own * 512 + j_own] = h_reg;
    grid.sync();
  }
}

// --------------------------- batched scores --------------------------------
// enc: 1600 blocks (32 b x 50 chunks of 8 s); usr: 800 blocks (32 b x 25 x 8).
// Per block: stage q_b (32 t x 512 d bf16 = 32KB LDS), wave handles 2 s, loops t.
__global__ __launch_bounds__(256) void k_scores(const us* __restrict__ Qall,
                                                const us* __restrict__ pkc,
                                                const us* __restrict__ pku,
                                                const float* __restrict__ wec,
                                                const float* __restrict__ bec,
                                                const float* __restrict__ weu,
                                                const float* __restrict__ beu,
                                                const int* __restrict__ src_mask,
                                                float* __restrict__ sc_enc,
                                                float* __restrict__ sc_usr) {
  __shared__ us q[32 * 512];
  const int bid = blockIdx.x;
  const bool enc = bid < 1600;
  int b, s0, qoff;
  if (enc) { b = bid / 50; s0 = (bid % 50) * 8; qoff = 0; }
  else { int j = bid - 1600; b = j / 25; s0 = (j % 25) * 8; qoff = 512; }
  for (int i = threadIdx.x; i < 2048; i += 256) {
    int tt = i >> 6, c8 = (i & 63) * 8;
    ((uint4*)q)[i] = *(const uint4*)(Qall + (size_t)(tt * 32 + b) * 1024 + qoff + c8);
  }
  __syncthreads();
  const int w = threadIdx.x >> 6, lane = threadIdx.x & 63;
  const int d0 = lane * 8;
  const float* we = enc ? wec : weu;
  float4 w0 = *(const float4*)(we + d0);
  float4 w1 = *(const float4*)(we + d0 + 4);
  float bias = enc ? bec[0] : beu[0];
#pragma unroll
  for (int sq = 0; sq < 2; ++sq) {
    int s = s0 + w * 2 + sq;
    const us* pk = enc ? pkc + ((size_t)b * 400 + s) * 512 : pku + ((size_t)b * 200 + s) * 512;
    uint4 pkv = *(const uint4*)(pk + d0);
    float pkf[8];
    pkf[0] = bf2f((us)(pkv.x & 0xffff)); pkf[1] = bf2f((us)(pkv.x >> 16));
    pkf[2] = bf2f((us)(pkv.y & 0xffff)); pkf[3] = bf2f((us)(pkv.y >> 16));
    pkf[4] = bf2f((us)(pkv.z & 0xffff)); pkf[5] = bf2f((us)(pkv.z >> 16));
    pkf[6] = bf2f((us)(pkv.w & 0xffff)); pkf[7] = bf2f((us)(pkv.w >> 16));
    int masked = enc ? (src_mask[b * 400 + s] == 0) : 0;
    for (int t = 0; t < 32; ++t) {
      short8 qv = *(const short8*)(q + t * 512 + d0);
      float acc =
          ftanh(bf2f((us)qv[0]) + pkf[0]) * w0.x +
          ftanh(bf2f((us)qv[1]) + pkf[1]) * w0.y +
          ftanh(bf2f((us)qv[2]) + pkf[2]) * w0.z +
          ftanh(bf2f((us)qv[3]) + pkf[3]) * w0.w +
          ftanh(bf2f((us)qv[4]) + pkf[4]) * w1.x +
          ftanh(bf2f((us)qv[5]) + pkf[5]) * w1.y +
          ftanh(bf2f((us)qv[6]) + pkf[6]) * w1.z +
          ftanh(bf2f((us)qv[7]) + pkf[7]) * w1.w;
#pragma unroll
      for (int m = 1; m < 64; m <<= 1) acc += __shfl_xor(acc, m, 64);
      if (lane == 0) {
        float v = acc + bias;
        if (enc) sc_enc[(size_t)(t * 32 + b) * 400 + s] = masked ? -1e9f : v;
        else sc_usr[(size_t)(t * 32 + b) * 200 + s] = v;
      }
    }
  }
}

// --------------------------- batched softmax -------------------------------
__device__ __forceinline__ float bmax256(float v, float* r4, int tid) {
#pragma unroll
  for (int m = 1; m < 64; m <<= 1) v = fmaxf(v, __shfl_xor(v, m, 64));
  if ((tid & 63) == 0) r4[tid >> 6] = v;
  __syncthreads();
  float x = fmaxf(fmaxf(r4[0], r4[1]), fmaxf(r4[2], r4[3]));
  __syncthreads();
  return x;
}
__device__ __forceinline__ float bsum256(float v, float* r4, int tid) {
#pragma unroll
  for (int m = 1; m < 64; m <<= 1) v += __shfl_xor(v, m, 64);
  if ((tid & 63) == 0) r4[tid >> 6] = v;
  __syncthreads();
  float x = r4[0] + r4[1] + r4[2] + r4[3];
  __syncthreads();
  return x;
}

// grid 2048: r<1024 -> enc row r=t*32+b -> AC [b][t][416] bf16 (+cp_acc init);
//            r>=1024 -> usr row -> AU [b][t][224] bf16 + aual f32
__global__ __launch_bounds__(256) void k_softmax(const float* __restrict__ sc_enc,
                                                 const float* __restrict__ sc_usr,
                                                 const float* __restrict__ bg,
                                                 us* __restrict__ AC,
                                                 us* __restrict__ AU,
                                                 float* __restrict__ aual,
                                                 float* __restrict__ cp_acc) {
  __shared__ float r4[4];
  int r = blockIdx.x, tid = threadIdx.x;
  if (r < 1024) {
    int t = r >> 5, b = r & 31;
    float v0 = (tid < 400) ? sc_enc[(size_t)r * 400 + tid] : -3e38f;
    float v1 = (tid + 256 < 400) ? sc_enc[(size_t)r * 400 + tid + 256] : -3e38f;
    float mx = bmax256(fmaxf(v0, v1), r4, tid);
    float e0 = (tid < 400) ? __expf(v0 - mx) : 0.f;
    float e1 = (tid + 256 < 400) ? __expf(v1 - mx) : 0.f;
    float inv = 1.f / bsum256(e0 + e1, r4, tid);
    us* ACb = AC + (size_t)(b * 32 + t) * 416;
    if (tid < 400) ACb[tid] = f2bf(e0 * inv);
    int s2 = tid + 256;
    if (s2 < 400) ACb[s2] = f2bf(e1 * inv);
    else if (s2 < 416) ACb[s2] = 0;
    if (tid == 0) cp_acc[r] = bg[0];
  } else {
    int rr = r - 1024;
    int t = rr >> 5, b = rr & 31;
    float v0 = (tid < 200) ? sc_usr[(size_t)rr * 200 + tid] : -3e38f;
    float mx = bmax256(v0, r4, tid);
    float e0 = (tid < 200) ? __expf(v0 - mx) : 0.f;
    float inv = 1.f / bsum256(e0, r4, tid);
    us* AUb = AU + (size_t)(b * 32 + t) * 224;
    if (tid < 200) {
      float a = e0 * inv;
      AUb[tid] = f2bf(a);
      aual[(size_t)rr * 200 + tid] = a;
    } else if (tid < 224) {
      AUb[tid] = 0;
    }
  }
}

// --------------------------- batched ctx GEMM ------------------------------
// Per b: C[32 t][N] = A_b[32][Kp] @ (BT_b[N][Kp])^T. Epilogue: write bf16 into
// catall cols [catOff, catOff+Nvalid) and accumulate gate partials (cp_acc).
__global__ __launch_bounds__(256) void k_ctx(const us* __restrict__ A,
                                             const us* __restrict__ BT,
                                             const float* __restrict__ Wg,
                                             us* __restrict__ catall,
                                             float* __restrict__ cp_acc,
                                             int N, int Kp, int catOff, int wgOff,
                                             int Nvalid) {
  __shared__ us As[32 * 32];
  __shared__ us Bs[128 * 32];
  __shared__ float gaccs[32];
  const int b = blockIdx.y, n0 = blockIdx.x * 128;
  const us* Ab = A + (size_t)b * 32 * Kp;
  const us* Bb = BT + (size_t)b * N * Kp;
  const int tid = threadIdx.x, lane = tid & 63, w = tid >> 6;
  if (tid < 32) gaccs[tid] = 0.f;
  f32x4 acc[2][2] = {};
  for (int kk = 0; kk < Kp; kk += 32) {
    uint4 av, bv0, bv1;
    if (tid < 128) av = *(const uint4*)(Ab + (size_t)(tid >> 2) * Kp + kk + (tid & 3) * 8);
    {
      int i0 = tid * 2, row0 = i0 >> 2, c0 = (i0 & 3) * 8;
      int i1 = tid * 2 + 1, row1 = i1 >> 2, c1 = (i1 & 3) * 8;
      int nr0 = n0 + row0; if (nr0 > N - 1) nr0 = N - 1;
      int nr1 = n0 + row1; if (nr1 > N - 1) nr1 = N - 1;
      bv0 = *(const uint4*)(Bb + (size_t)nr0 * Kp + kk + c0);
      bv1 = *(const uint4*)(Bb + (size_t)nr1 * Kp + kk + c1);
    }
    __syncthreads();
    if (tid < 128) ((uint4*)As)[tid] = av;
    ((uint4*)Bs)[tid * 2] = bv0;
    ((uint4*)Bs)[tid * 2 + 1] = bv1;
    __syncthreads();
    short8 a0 = *(const short8*)(As + ((lane & 15)) * 32 + (lane >> 4) * 8);
    short8 a1 = *(const short8*)(As + (16 + (lane & 15)) * 32 + (lane >> 4) * 8);
#pragma unroll
    for (int q = 0; q < 2; ++q) {
      short8 bf_ = *(const short8*)(Bs + ((w * 2 + q) * 16 + (lane & 15)) * 32 + (lane >> 4) * 8);
      acc[0][q] = __builtin_amdgcn_mfma_f32_16x16x32_bf16(a0, bf_, acc[0][q], 0, 0, 0);
      acc[1][q] = __builtin_amdgcn_mfma_f32_16x16x32_bf16(a1, bf_, acc[1][q], 0, 0, 0);
    }
  }
#pragma unroll
  for (int mt = 0; mt < 2; ++mt)
#pragma unroll
    for (int q = 0; q < 2; ++q)
#pragma unroll
      for (int reg = 0; reg < 4; ++reg) {
        int t_ = mt * 16 + (lane >> 4) * 4 + reg;
        int c = n0 + (w * 2 + q) * 16 + (lane & 15);
        if (c < Nvalid) {
          float v = acc[mt][q][reg];
          catall[(size_t)(t_ * 32 + b) * 2144 + catOff + c] = f2bf(v);
          atomicAdd(&gaccs[t_], v * Wg[wgOff + c]);
        }
      }
  __syncthreads();
  if (tid < 32) atomicAdd(&cp_acc[tid * 32 + b], gaccs[tid]);
}

// --------------------------- cat h/ue + gate finish ------------------------
__global__ __launch_bounds__(256) void k_catgate(const us* __restrict__ hball,
                                                 const float* __restrict__ hfall,
                                                 const float* __restrict__ ue,
                                                 const float* __restrict__ Wg,
                                                 const float* __restrict__ cp_acc,
                                                 us* __restrict__ catall,
                                                 float* __restrict__ cp_all) {
  __shared__ float r4[4];
  int r = blockIdx.x, tid = threadIdx.x;
  int t = r >> 5, b = r & 31;
  us* row = catall + (size_t)r * 2144;
  const us* hb = hball + (size_t)(t + 1) * 16384 + b * 512;
  row[tid] = hb[tid];
  row[256 + tid] = hb[256 + tid];
  float gp = 0.f;
  for (int i = tid; i < 512; i += 256)
    gp += hfall[(size_t)t * 16384 + b * 512 + i] * Wg[1024 + i];
  for (int i = tid; i < 308; i += 256)
    row[1836 + i] = (i < 300) ? f2bf(ue[b * 300 + i]) : (us)0;
  float gtot = bsum256(gp, r4, tid);
  if (tid == 0) cp_all[r] = fsigmoid(gtot + cp_acc[r]);
}

// --------------------------- finalize --------------------------------------
__global__ __launch_bounds__(256) void k_finalize(float* __restrict__ out,
                                                  const float* __restrict__ rowsum,
                                                  const float* __restrict__ cp_all,
                                                  const float* __restrict__ au_all,
                                                  const int* __restrict__ sv) {
  int r = blockIdx.x;  // t*32+b
  int t = threadIdx.x;
  int b = r & 31, tt = r >> 5;
  float cp = cp_all[r];
  float scale = (1.f - cp) / rowsum[r];
  float* base = out + (size_t)(b * 32 + tt) * 50200;
  float4* b4 = (float4*)base;
  for (int i = t; i < 12550; i += 256) {
    if (i < 12500) {
      float4 v = b4[i];
      v.x *= scale; v.y *= scale; v.z *= scale; v.w *= scale;
      b4[i] = v;
    } else {
      b4[i] = make_float4(0.f, 0.f, 0.f, 0.f);
    }
  }
  __syncthreads();
  if (t < 200) {
    int idx = sv[b * 200 + t];
    atomicAdd(base + idx, cp * au_all[(size_t)r * 200 + t]);
  }
}

// ---------------------------------------------------------------------------

extern "C" void kernel_launch(void* const* d_in, const int* in_sizes, int n_in,
                              void* d_out, int out_size, void* d_ws, size_t ws_size,
                              hipStream_t stream) {
  (void)in_sizes; (void)n_in; (void)out_size; (void)ws_size;
  const float* enc = (const float*)d_in[0];
  const float* hidden0 = (const float*)d_in[1];
  const float* user_embed = (const float*)d_in[2];
  const float* W_embed = (const float*)d_in[3];
  const float* W_ih = (const float*)d_in[4];
  const float* W_hh = (const float*)d_in[5];
  const float* b_ih = (const float*)d_in[6];
  const float* b_hh = (const float*)d_in[7];
  const float* Wk_c = (const float*)d_in[8];
  const float* bk_c = (const float*)d_in[9];
  const float* Wq_c = (const float*)d_in[10];
  const float* bq_c = (const float*)d_in[11];
  const float* we_c = (const float*)d_in[12];
  const float* be_c = (const float*)d_in[13];
  const float* Wk_u = (const float*)d_in[14];
  const float* bk_u = (const float*)d_in[15];
  const float* Wq_u = (const float*)d_in[16];
  const float* bq_u = (const float*)d_in[17];
  const float* we_u = (const float*)d_in[18];
  const float* be_u = (const float*)d_in[19];
  const float* Wc = (const float*)d_in[20];
  const float* Wg = (const float*)d_in[21];
  const float* bg = (const float*)d_in[22];
  const float* Wgen = (const float*)d_in[23];
  const int* src_mask = (const int*)d_in[24];
  const int* tgt = (const int*)d_in[25];
  const int* sv = (const int*)d_in[26];
  float* out = (float*)d_out;

  // ---------------- workspace layout (~121 MB, with unions) ----------------
  char* base = (char*)d_ws;
  size_t off = 0;
  auto take = [&](size_t bytes) {
    char* p = base + off;
    off += (bytes + 255) & ~(size_t)255;
    return p;
  };
  us* WT = (us*)take(50000ull * 512 * 2);                 // Wgen^T bf16
  char* R0 = take(32ull * 1024 * 416 * 2);                // encb -> encTp
  us* encb = (us*)R0;                                     // [12800][1024]
  us* encTp = (us*)R0;                                    // [b][1024][416]
  char* RCD = take(12800ull * 512 * 2 + 6400ull * 512 * 2);
  us* pkc = (us*)RCD;                                     // [12800][512]
  us* pku = (us*)(RCD + 12800ull * 512 * 2);              // [6400][512]
  us* AC = (us*)RCD;                                      // [32][32][416] (after scores)
  us* AU = (us*)(RCD + 860160);                           // [32][32][224]
  float* aual = (float*)(RCD + 860160 + 458752);          // [1024][200]
  us* catall = (us*)(RCD + 860160 + 458752 + 819200);     // [1024][2144]
  us* chb = (us*)(RCD + 860160 + 458752 + 819200 + 4390912);  // [1024][512]
  char* RU = take(6400ull * 320 * 2);                     // uve -> sc_enc/sc_usr
  us* uve = (us*)RU;
  float* sc_enc = (float*)RU;                             // [1024][400]
  float* sc_usr = (float*)(RU + 1024ull * 400 * 4);       // [1024][200]
  us* uveTp = (us*)take(32ull * 320 * 224 * 2);           // [b][320][224]
  char* RG = take(2700000);                               // WkcT|WihT|xe -> Qall
  us* WkcT = (us*)RG;                                     // [512][1024]
  us* WihT = (us*)(RG + 1048576);                         // [1536][320]
  us* xe = (us*)(RG + 1048576 + 983040);                  // [1024][320]
  us* Qall = (us*)RG;                                     // [1024][1024] (after gib)
  us* WkuT = (us*)take(512ull * 320 * 2);
  us* WqcuT = (us*)take(1024ull * 512 * 2);
  us* WcT = (us*)take(512ull * 2144 * 2);
  us* WhhF = (us*)take(1536ull * 512 * 2);                // fragment-packed Whh
  us* gib = (us*)take(1024ull * 1536 * 2);
  us* hball = (us*)take(33ull * 16384 * 2);
  float* hfall = (float*)take(32ull * 16384 * 4);
  float* bqcu = (float*)take(1024 * 4);
  float* cp_acc = (float*)take(1024 * 4);
  float* cp_all = (float*)take(1024 * 4);
  float* rsum = (float*)take(1024 * 4);

  // ---------------- precompute ----------------
  hipMemcpyAsync(bqcu, bq_c, 512 * 4, hipMemcpyDeviceToDevice, stream);
  hipMemcpyAsync(bqcu + 512, bq_u, 512 * 4, hipMemcpyDeviceToDevice, stream);
  hipMemsetAsync(rsum, 0, 1024 * 4, stream);

  k_cast_f2b<<<2048, 256, 0, stream>>>(enc, encb, 3276800);
  k_tcastX<<<dim3(1563, 16, 1), 256, 0, stream>>>(Wgen, WT, 512, 50000, 512, 0, 0);
  k_tcastX<<<dim3(16, 32, 1), 256, 0, stream>>>(Wk_c, WkcT, 1024, 512, 1024, 0, 0);
  k_tcastX<<<dim3(16, 10, 1), 256, 0, stream>>>(Wk_u, WkuT, 300, 512, 320, 0, 0);
  k_tcastX<<<dim3(16, 16, 1), 256, 0, stream>>>(Wq_c, WqcuT, 512, 512, 512, 0, 0);
  k_tcastX<<<dim3(16, 16, 1), 256, 0, stream>>>(Wq_u, WqcuT + 512ull * 512, 512, 512, 512, 0, 0);
  k_tcastX<<<dim3(16, 67, 1), 256, 0, stream>>>(Wc, WcT, 2136, 512, 2144, 0, 0);
  k_castpad<<<1536, 64, 0, stream>>>(W_ih, WihT, 300, 320);
  k_fragpack<<<dim3(96, 16), 64, 0, stream>>>(W_hh, WhhF);
  k_gather_xe<<<1024, 64, 0, stream>>>(W_embed, tgt, xe);
  k_gather_uve<<<6400, 64, 0, stream>>>(W_embed, sv, uve);

  // proj keys + gi (batched GEMMs)
  gemm_bt<0><<<200, 512, 0, stream>>>(encb, WkcT, 12800, 512, 1024, 4, bk_c, pkc, nullptr, nullptr);
  gemm_bt<0><<<100, 512, 0, stream>>>(uve, WkuT, 6400, 512, 320, 4, bk_u, pku, nullptr, nullptr);
  gemm_bt<0><<<48, 512, 0, stream>>>(xe, WihT, 1024, 1536, 320, 12, b_ih, gib, nullptr, nullptr);

  // transposes for ctx GEMMs (encTp overwrites encb AFTER pkc GEMM)
  k_tcastX<<<dim3(32, 13, 32), 256, 0, stream>>>(enc, encTp, 400, 1024, 416,
                                                 400ull * 1024, 1024ull * 416);
  k_tcastXb<<<dim3(10, 7, 32), 256, 0, stream>>>(uve, uveTp, 200, 320, 224,
                                                 200ull * 320, 320ull * 224);

  // ---------------- sequential GRU (cooperative, 33 grid syncs) ----------------
  GP gp;
  gp.frag = WhhF; gp.gib = gib; gp.bhh = b_hh; gp.hidden0 = hidden0;
  gp.hball = hball; gp.hfall = hfall;
  void* kargs[] = {(void*)&gp};
  hipLaunchCooperativeKernel((const void*)k_gru, dim3(32), dim3(512), kargs, 0, stream);

  // ---------------- batched attention + output ----------------
  // Qall = H_all @ [Wq_c|Wq_u] + bias  (overwrites WkcT/WihT/xe region)
  gemm_bt<0><<<32, 512, 0, stream>>>(hball + 16384, WqcuT, 1024, 1024, 512, 8, bqcu,
                                     Qall, nullptr, nullptr);
  k_scores<<<2400, 256, 0, stream>>>(Qall, pkc, pku, we_c, be_c, we_u, be_u,
                                     src_mask, sc_enc, sc_usr);
  k_softmax<<<2048, 256, 0, stream>>>(sc_enc, sc_usr, bg, AC, AU, aual, cp_acc);
  k_ctx<<<dim3(8, 32), 256, 0, stream>>>(AC, encTp, Wg, catall, cp_acc,
                                         1024, 416, 512, 0, 1024);
  k_ctx<<<dim3(3, 32), 256, 0, stream>>>(AU, uveTp, Wg, catall, cp_acc,
                                         320, 224, 1536, 1536, 300);
  k_catgate<<<1024, 256, 0, stream>>>(hball, hfall, user_embed, Wg, cp_acc,
                                      catall, cp_all);
  gemm_bt<2><<<16, 512, 0, stream>>>(catall, WcT, 1024, 512, 2144, 4, nullptr, chb,
                                     nullptr, nullptr);
  gemm_bt<1><<<4 * 391, 512, 0, stream>>>(chb, WT, 1024, 50000, 512, 391, nullptr,
                                          nullptr, out, rsum);
  k_finalize<<<1024, 256, 0, stream>>>(out, rsum, cp_all, aual, sv);
}

// Round 4
// 892.279 us; speedup vs baseline: 6.4517x; 1.2279x over previous
//
#include <hip/hip_runtime.h>

// ---------------------------------------------------------------------------
// Pointer-generator decoder. B=32 S=400 H=512 E=300 Vs=200 T=32 EN=50000 V=50200
// Round 4: GRU -> 8-block weights-in-register kernel with flag barrier
// (no grid.sync, no per-step L2 weight refetch). Rest as round 3.
// ---------------------------------------------------------------------------

typedef __attribute__((ext_vector_type(8))) short short8;
typedef __attribute__((ext_vector_type(4))) float f32x4;
typedef unsigned short us;

__device__ __forceinline__ float bf2f(us u) {
  return __uint_as_float(((unsigned)u) << 16);
}
__device__ __forceinline__ us f2bf(float f) {
  unsigned x = __float_as_uint(f);
  unsigned r = x + 0x7fffu + ((x >> 16) & 1u);
  return (us)(r >> 16);
}
__device__ __forceinline__ float fsigmoid(float x) { return 1.f / (1.f + __expf(-x)); }
__device__ __forceinline__ float ftanh(float x) {
  float t = __expf(-2.f * fabsf(x));
  float r = (1.f - t) / (1.f + t);
  return x >= 0.f ? r : -r;
}

// --------------------------- precompute kernels ----------------------------

__global__ __launch_bounds__(256) void k_cast_f2b(const float* __restrict__ src,
                                                  us* __restrict__ dst, int n4) {
  int stride = gridDim.x * blockDim.x;
  for (int i = blockIdx.x * blockDim.x + threadIdx.x; i < n4; i += stride) {
    float4 v = ((const float4*)src)[i];
    ushort4 o;
    o.x = f2bf(v.x); o.y = f2bf(v.y); o.z = f2bf(v.z); o.w = f2bf(v.w);
    ((ushort4*)dst)[i] = o;
  }
}

// transpose + cast (f32 src): src [R][C] -> dst [C][Rpad] bf16, batched over z
__global__ __launch_bounds__(256) void k_tcastX(const float* __restrict__ src0,
                                                us* __restrict__ dst0,
                                                int R, int C, int Rpad,
                                                size_t srcB, size_t dstB) {
  __shared__ float tile[32][33];
  const float* src = src0 + (size_t)blockIdx.z * srcB;
  us* dst = dst0 + (size_t)blockIdx.z * dstB;
  int c0 = blockIdx.x * 32, r0 = blockIdx.y * 32;
  int tx = threadIdx.x & 31, ty = threadIdx.x >> 5;
#pragma unroll
  for (int i = 0; i < 4; ++i) {
    int r = r0 + ty + i * 8, c = c0 + tx;
    tile[ty + i * 8][tx] = (r < R && c < C) ? src[(size_t)r * C + c] : 0.f;
  }
  __syncthreads();
#pragma unroll
  for (int i = 0; i < 4; ++i) {
    int c = c0 + ty + i * 8, rr = r0 + tx;
    if (c < C && rr < Rpad) dst[(size_t)c * Rpad + rr] = f2bf(tile[tx][ty + i * 8]);
  }
}

// transpose (bf16 src): src [R][C] bf16 -> dst [C][Rpad] bf16, batched over z
__global__ __launch_bounds__(256) void k_tcastXb(const us* __restrict__ src0,
                                                 us* __restrict__ dst0,
                                                 int R, int C, int Rpad,
                                                 size_t srcB, size_t dstB) {
  __shared__ us tile[32][33];
  const us* src = src0 + (size_t)blockIdx.z * srcB;
  us* dst = dst0 + (size_t)blockIdx.z * dstB;
  int c0 = blockIdx.x * 32, r0 = blockIdx.y * 32;
  int tx = threadIdx.x & 31, ty = threadIdx.x >> 5;
#pragma unroll
  for (int i = 0; i < 4; ++i) {
    int r = r0 + ty + i * 8, c = c0 + tx;
    tile[ty + i * 8][tx] = (r < R && c < C) ? src[(size_t)r * C + c] : (us)0;
  }
  __syncthreads();
#pragma unroll
  for (int i = 0; i < 4; ++i) {
    int c = c0 + ty + i * 8, rr = r0 + tx;
    if (c < C && rr < Rpad) dst[(size_t)c * Rpad + rr] = tile[tx][ty + i * 8];
  }
}

__global__ __launch_bounds__(64) void k_castpad(const float* __restrict__ src,
                                                us* __restrict__ dst,
                                                int C, int Cpad) {
  int row = blockIdx.x;
  for (int k = threadIdx.x; k < Cpad; k += 64)
    dst[(size_t)row * Cpad + k] = (k < C) ? f2bf(src[(size_t)row * C + k]) : (us)0;
}

__global__ __launch_bounds__(64) void k_gather_xe(const float* __restrict__ W_embed,
                                                  const int* __restrict__ tgt,
                                                  us* __restrict__ xe) {
  int r = blockIdx.x;
  int t = r >> 5, b = r & 31;
  int tok = (t == 0) ? 1 : tgt[b * 32 + (t - 1)];
  const float* src = W_embed + (size_t)tok * 300;
  for (int k = threadIdx.x; k < 320; k += 64)
    xe[(size_t)r * 320 + k] = (k < 300) ? f2bf(src[k]) : (us)0;
}

__global__ __launch_bounds__(64) void k_gather_uve(const float* __restrict__ W_embed,
                                                   const int* __restrict__ sv,
                                                   us* __restrict__ uve) {
  int row = blockIdx.x;  // b*200+v
  int tok = sv[row];
  const float* src = W_embed + (size_t)tok * 300;
  for (int k = threadIdx.x; k < 320; k += 64)
    uve[(size_t)row * 320 + k] = (k < 300) ? f2bf(src[k]) : (us)0;
}

// pack Whh [1536][512] f32 into per-block MFMA B-fragment order (bf16):
// block q owns rows {g*512 + q*64 + jj}; F[(((q*12+lt)*16+kt)*64+l)*8 + i]
__global__ __launch_bounds__(64) void k_fragpack(const float* __restrict__ W,
                                                 us* __restrict__ F) {
  int q = blockIdx.x, lt = blockIdx.y, kt = blockIdx.z, l = threadIdx.x;
  int localrow = lt * 16 + (l & 15);
  int g = localrow >> 6, jj = localrow & 63;
  const float* src = W + (size_t)(g * 512 + q * 64 + jj) * 512 + kt * 32 + (l >> 4) * 8;
  us* dst = F + (((size_t)(q * 12 + lt) * 16 + kt) * 64 + l) * 8;
#pragma unroll
  for (int i = 0; i < 8; ++i) dst[i] = f2bf(src[i]);
}

// --------------------------- big MFMA GEMM ---------------------------------
template <int MODE>
__global__ __launch_bounds__(512) void gemm_bt(const us* __restrict__ A,
                                               const us* __restrict__ BT,
                                               int M, int N, int K, int Ntiles,
                                               const float* __restrict__ bias,
                                               us* __restrict__ outB,
                                               float* __restrict__ outF,
                                               float* __restrict__ rowsum) {
  __shared__ us As[256 * 32];
  __shared__ us Bs[128 * 32];
  __shared__ float rs[256];
  const int tid = threadIdx.x;
  const int lane = tid & 63, wid = tid >> 6;
  const int wr = wid >> 1, wc = wid & 1;
  const int bx = blockIdx.x;
  const int mt = bx / Ntiles, nt = bx - mt * Ntiles;
  const int m0 = mt * 256, n0 = nt * 128;
  f32x4 acc[4][4] = {};
  for (int kk = 0; kk < K; kk += 32) {
    uint4 av0, av1, bv;
    {
      int c = tid, row = c >> 2, c8 = (c & 3) * 8;
      av0 = *(const uint4*)(A + (size_t)(m0 + row) * K + kk + c8);
      c = tid + 512; row = c >> 2; c8 = (c & 3) * 8;
      av1 = *(const uint4*)(A + (size_t)(m0 + row) * K + kk + c8);
      c = tid; row = c >> 2; c8 = (c & 3) * 8;
      int nr = n0 + row; if (nr > N - 1) nr = N - 1;
      bv = *(const uint4*)(BT + (size_t)nr * K + kk + c8);
    }
    __syncthreads();
    ((uint4*)As)[tid] = av0;
    ((uint4*)As)[tid + 512] = av1;
    ((uint4*)Bs)[tid] = bv;
    __syncthreads();
    short8 af[4], bfr[4];
#pragma unroll
    for (int m = 0; m < 4; ++m)
      af[m] = *(const short8*)(As + (wr * 64 + m * 16 + (lane & 15)) * 32 + (lane >> 4) * 8);
#pragma unroll
    for (int n = 0; n < 4; ++n)
      bfr[n] = *(const short8*)(Bs + (wc * 64 + n * 16 + (lane & 15)) * 32 + (lane >> 4) * 8);
#pragma unroll
    for (int m = 0; m < 4; ++m)
#pragma unroll
      for (int n = 0; n < 4; ++n)
        acc[m][n] = __builtin_amdgcn_mfma_f32_16x16x32_bf16(af[m], bfr[n], acc[m][n], 0, 0, 0);
  }
  if (MODE == 0 || MODE == 2) {
#pragma unroll
    for (int m = 0; m < 4; ++m)
#pragma unroll
      for (int n = 0; n < 4; ++n)
#pragma unroll
        for (int reg = 0; reg < 4; ++reg) {
          int r = m0 + wr * 64 + m * 16 + (lane >> 4) * 4 + reg;
          int c = n0 + wc * 64 + n * 16 + (lane & 15);
          float v = acc[m][n][reg];
          if (MODE == 0) v += bias[c];
          else v = ftanh(v);
          outB[(size_t)r * N + c] = f2bf(v);
        }
  } else {
    if (tid < 256) rs[tid] = 0.f;
    __syncthreads();
#pragma unroll
    for (int m = 0; m < 4; ++m) {
#pragma unroll
      for (int reg = 0; reg < 4; ++reg) {
        int rloc = wr * 64 + m * 16 + (lane >> 4) * 4 + reg;
        int r = m0 + rloc;
        size_t obase = (size_t)((r & 31) * 32 + (r >> 5)) * 50200;
        float s = 0.f;
#pragma unroll
        for (int n = 0; n < 4; ++n) {
          int c = n0 + wc * 64 + n * 16 + (lane & 15);
          if (c < N) {
            float e = __expf(acc[m][n][reg]);
            outF[obase + c] = e;
            s += e;
          }
        }
        s += __shfl_xor(s, 1, 64); s += __shfl_xor(s, 2, 64);
        s += __shfl_xor(s, 4, 64); s += __shfl_xor(s, 8, 64);
        if ((lane & 15) == 0) atomicAdd(&rs[rloc], s);
      }
    }
    __syncthreads();
    if (tid < 256) atomicAdd(&rowsum[m0 + tid], rs[tid]);
  }
}

// --------------------------- GRU: 8 blocks, weights in registers -----------
// Block q owns j in [64q, 64q+64) of all 3 gates (192 Whh rows as B-frags).
// Flag barrier: arrive[t] counts blocks done producing hball[t+1].
struct GP {
  const us* frag; const us* gib; const float* bhh; const float* hidden0;
  us* hball;    // [33][32][512] bf16
  float* hfall; // [32][32][512] f32
  int* arrive;  // [32]
};

__global__ __launch_bounds__(768, 1) void k_gru(GP P) {
  const int q = blockIdx.x;
  const int tid = threadIdx.x;
  const int lane = tid & 63, w = tid >> 6;  // w = local n-tile in [0,12)
  __shared__ us hs[32 * 512];     // swizzled h_prev (32 KB)
  __shared__ float gh[192 * 33];  // gh partial-free result [col][b]
  // load this wave's 16 B-fragments once (64 VGPRs)
  short8 bfr[16];
  {
    const us* fb = P.frag + (((size_t)(q * 12 + w) * 16) * 64 + lane) * 8;
#pragma unroll
    for (int kt = 0; kt < 16; ++kt) bfr[kt] = *(const short8*)(fb + (size_t)kt * 512);
  }
  // f32 carry h in registers: thread owns items i = tid + s*768 (i<2048)
  float hprev[3];
#pragma unroll
  for (int s = 0; s < 3; ++s) {
    int i = tid + s * 768;
    if (i < 2048) {
      int b = i >> 6, jj = i & 63;
      hprev[s] = P.hidden0[b * 512 + q * 64 + jj];
    }
  }
  const int sw = (lane & 7) << 3;  // A-frag read swizzle (us units)
  for (int t = 0; t < 32; ++t) {
    if (t > 0) {
      if (tid == 0) {
        while (__hip_atomic_load(P.arrive + (t - 1), __ATOMIC_ACQUIRE,
                                 __HIP_MEMORY_SCOPE_AGENT) < 8) {
          __builtin_amdgcn_s_sleep(1);
        }
      }
      __syncthreads();
    }
    // stage h_prev into LDS with per-row XOR swizzle (16B granularity)
    const us* hp = P.hball + (size_t)t * 16384;
    for (int i = tid; i < 2048; i += 768)
      ((uint4*)hs)[i ^ ((i >> 6) & 7)] = *(const uint4*)(hp + i * 8);
    __syncthreads();
    f32x4 acc0 = {}, acc1 = {};
#pragma unroll
    for (int kt = 0; kt < 16; ++kt) {
      int base0 = ((lane & 15) * 512 + kt * 32 + (lane >> 4) * 8) ^ sw;
      int base1 = (((lane & 15) + 16) * 512 + kt * 32 + (lane >> 4) * 8) ^ sw;
      short8 a0 = *(const short8*)(hs + base0);
      short8 a1 = *(const short8*)(hs + base1);
      acc0 = __builtin_amdgcn_mfma_f32_16x16x32_bf16(a0, bfr[kt], acc0, 0, 0, 0);
      acc1 = __builtin_amdgcn_mfma_f32_16x16x32_bf16(a1, bfr[kt], acc1, 0, 0, 0);
    }
    {
      int col = w * 16 + (lane & 15);
#pragma unroll
      for (int reg = 0; reg < 4; ++reg) {
        gh[col * 33 + ((lane >> 4) * 4 + reg)] = acc0[reg];
        gh[col * 33 + (16 + (lane >> 4) * 4 + reg)] = acc1[reg];
      }
    }
    __syncthreads();
    // elementwise GRU update for this block's 2048 (b,jj) items
    us* hbn = P.hball + (size_t)(t + 1) * 16384;
    float* hfn = P.hfall + (size_t)t * 16384;
#pragma unroll
    for (int s = 0; s < 3; ++s) {
      int i = tid + s * 768;
      if (i < 2048) {
        int b = i >> 6, jj = i & 63;
        int j = q * 64 + jj;
        float g0 = gh[jj * 33 + b] + P.bhh[j];
        float g1 = gh[(64 + jj) * 33 + b] + P.bhh[512 + j];
        float g2 = gh[(128 + jj) * 33 + b] + P.bhh[1024 + j];
        size_t gbase = (size_t)(t * 32 + b) * 1536;
        float r_ = fsigmoid(bf2f(P.gib[gbase + j]) + g0);
        float z_ = fsigmoid(bf2f(P.gib[gbase + 512 + j]) + g1);
        float n_ = ftanh(bf2f(P.gib[gbase + 1024 + j]) + r_ * g2);
        float hv = (1.f - z_) * n_ + z_ * hprev[s];
        hprev[s] = hv;
        hbn[b * 512 + j] = f2bf(hv);
        hfn[b * 512 + j] = hv;
      }
    }
    __syncthreads();  // drains vmcnt: all global h stores complete
    if (tid == 0)
      __hip_atomic_fetch_add(P.arrive + t, 1, __ATOMIC_RELEASE,
                             __HIP_MEMORY_SCOPE_AGENT);
  }
}

// --------------------------- batched scores --------------------------------
__global__ __launch_bounds__(256) void k_scores(const us* __restrict__ Qall,
                                                const us* __restrict__ pkc,
                                                const us* __restrict__ pku,
                                                const float* __restrict__ wec,
                                                const float* __restrict__ bec,
                                                const float* __restrict__ weu,
                                                const float* __restrict__ beu,
                                                const int* __restrict__ src_mask,
                                                float* __restrict__ sc_enc,
                                                float* __restrict__ sc_usr) {
  __shared__ us q[32 * 512];
  const int bid = blockIdx.x;
  const bool enc = bid < 1600;
  int b, s0, qoff;
  if (enc) { b = bid / 50; s0 = (bid % 50) * 8; qoff = 0; }
  else { int j = bid - 1600; b = j / 25; s0 = (j % 25) * 8; qoff = 512; }
  for (int i = threadIdx.x; i < 2048; i += 256) {
    int tt = i >> 6, c8 = (i & 63) * 8;
    ((uint4*)q)[i] = *(const uint4*)(Qall + (size_t)(tt * 32 + b) * 1024 + qoff + c8);
  }
  __syncthreads();
  const int w = threadIdx.x >> 6, lane = threadIdx.x & 63;
  const int d0 = lane * 8;
  const float* we = enc ? wec : weu;
  float4 w0 = *(const float4*)(we + d0);
  float4 w1 = *(const float4*)(we + d0 + 4);
  float bias = enc ? bec[0] : beu[0];
#pragma unroll
  for (int sq = 0; sq < 2; ++sq) {
    int s = s0 + w * 2 + sq;
    const us* pk = enc ? pkc + ((size_t)b * 400 + s) * 512 : pku + ((size_t)b * 200 + s) * 512;
    uint4 pkv = *(const uint4*)(pk + d0);
    float pkf[8];
    pkf[0] = bf2f((us)(pkv.x & 0xffff)); pkf[1] = bf2f((us)(pkv.x >> 16));
    pkf[2] = bf2f((us)(pkv.y & 0xffff)); pkf[3] = bf2f((us)(pkv.y >> 16));
    pkf[4] = bf2f((us)(pkv.z & 0xffff)); pkf[5] = bf2f((us)(pkv.z >> 16));
    pkf[6] = bf2f((us)(pkv.w & 0xffff)); pkf[7] = bf2f((us)(pkv.w >> 16));
    int masked = enc ? (src_mask[b * 400 + s] == 0) : 0;
    for (int t = 0; t < 32; ++t) {
      short8 qv = *(const short8*)(q + t * 512 + d0);
      float acc =
          ftanh(bf2f((us)qv[0]) + pkf[0]) * w0.x +
          ftanh(bf2f((us)qv[1]) + pkf[1]) * w0.y +
          ftanh(bf2f((us)qv[2]) + pkf[2]) * w0.z +
          ftanh(bf2f((us)qv[3]) + pkf[3]) * w0.w +
          ftanh(bf2f((us)qv[4]) + pkf[4]) * w1.x +
          ftanh(bf2f((us)qv[5]) + pkf[5]) * w1.y +
          ftanh(bf2f((us)qv[6]) + pkf[6]) * w1.z +
          ftanh(bf2f((us)qv[7]) + pkf[7]) * w1.w;
#pragma unroll
      for (int m = 1; m < 64; m <<= 1) acc += __shfl_xor(acc, m, 64);
      if (lane == 0) {
        float v = acc + bias;
        if (enc) sc_enc[(size_t)(t * 32 + b) * 400 + s] = masked ? -1e9f : v;
        else sc_usr[(size_t)(t * 32 + b) * 200 + s] = v;
      }
    }
  }
}

// --------------------------- batched softmax -------------------------------
__device__ __forceinline__ float bmax256(float v, float* r4, int tid) {
#pragma unroll
  for (int m = 1; m < 64; m <<= 1) v = fmaxf(v, __shfl_xor(v, m, 64));
  if ((tid & 63) == 0) r4[tid >> 6] = v;
  __syncthreads();
  float x = fmaxf(fmaxf(r4[0], r4[1]), fmaxf(r4[2], r4[3]));
  __syncthreads();
  return x;
}
__device__ __forceinline__ float bsum256(float v, float* r4, int tid) {
#pragma unroll
  for (int m = 1; m < 64; m <<= 1) v += __shfl_xor(v, m, 64);
  if ((tid & 63) == 0) r4[tid >> 6] = v;
  __syncthreads();
  float x = r4[0] + r4[1] + r4[2] + r4[3];
  __syncthreads();
  return x;
}

__global__ __launch_bounds__(256) void k_softmax(const float* __restrict__ sc_enc,
                                                 const float* __restrict__ sc_usr,
                                                 const float* __restrict__ bg,
                                                 us* __restrict__ AC,
                                                 us* __restrict__ AU,
                                                 float* __restrict__ aual,
                                                 float* __restrict__ cp_acc) {
  __shared__ float r4[4];
  int r = blockIdx.x, tid = threadIdx.x;
  if (r < 1024) {
    int t = r >> 5, b = r & 31;
    float v0 = (tid < 400) ? sc_enc[(size_t)r * 400 + tid] : -3e38f;
    float v1 = (tid + 256 < 400) ? sc_enc[(size_t)r * 400 + tid + 256] : -3e38f;
    float mx = bmax256(fmaxf(v0, v1), r4, tid);
    float e0 = (tid < 400) ? __expf(v0 - mx) : 0.f;
    float e1 = (tid + 256 < 400) ? __expf(v1 - mx) : 0.f;
    float inv = 1.f / bsum256(e0 + e1, r4, tid);
    us* ACb = AC + (size_t)(b * 32 + t) * 416;
    if (tid < 400) ACb[tid] = f2bf(e0 * inv);
    int s2 = tid + 256;
    if (s2 < 400) ACb[s2] = f2bf(e1 * inv);
    else if (s2 < 416) ACb[s2] = 0;
    if (tid == 0) cp_acc[r] = bg[0];
  } else {
    int rr = r - 1024;
    int t = rr >> 5, b = rr & 31;
    float v0 = (tid < 200) ? sc_usr[(size_t)rr * 200 + tid] : -3e38f;
    float mx = bmax256(v0, r4, tid);
    float e0 = (tid < 200) ? __expf(v0 - mx) : 0.f;
    float inv = 1.f / bsum256(e0, r4, tid);
    us* AUb = AU + (size_t)(b * 32 + t) * 224;
    if (tid < 200) {
      float a = e0 * inv;
      AUb[tid] = f2bf(a);
      aual[(size_t)rr * 200 + tid] = a;
    } else if (tid < 224) {
      AUb[tid] = 0;
    }
  }
}

// --------------------------- batched ctx GEMM ------------------------------
__global__ __launch_bounds__(256) void k_ctx(const us* __restrict__ A,
                                             const us* __restrict__ BT,
                                             const float* __restrict__ Wg,
                                             us* __restrict__ catall,
                                             float* __restrict__ cp_acc,
                                             int N, int Kp, int catOff, int wgOff,
                                             int Nvalid) {
  __shared__ us As[32 * 32];
  __shared__ us Bs[128 * 32];
  __shared__ float gaccs[32];
  const int b = blockIdx.y, n0 = blockIdx.x * 128;
  const us* Ab = A + (size_t)b * 32 * Kp;
  const us* Bb = BT + (size_t)b * N * Kp;
  const int tid = threadIdx.x, lane = tid & 63, w = tid >> 6;
  if (tid < 32) gaccs[tid] = 0.f;
  f32x4 acc[2][2] = {};
  for (int kk = 0; kk < Kp; kk += 32) {
    uint4 av, bv0, bv1;
    if (tid < 128) av = *(const uint4*)(Ab + (size_t)(tid >> 2) * Kp + kk + (tid & 3) * 8);
    {
      int i0 = tid * 2, row0 = i0 >> 2, c0 = (i0 & 3) * 8;
      int i1 = tid * 2 + 1, row1 = i1 >> 2, c1 = (i1 & 3) * 8;
      int nr0 = n0 + row0; if (nr0 > N - 1) nr0 = N - 1;
      int nr1 = n0 + row1; if (nr1 > N - 1) nr1 = N - 1;
      bv0 = *(const uint4*)(Bb + (size_t)nr0 * Kp + kk + c0);
      bv1 = *(const uint4*)(Bb + (size_t)nr1 * Kp + kk + c1);
    }
    __syncthreads();
    if (tid < 128) ((uint4*)As)[tid] = av;
    ((uint4*)Bs)[tid * 2] = bv0;
    ((uint4*)Bs)[tid * 2 + 1] = bv1;
    __syncthreads();
    short8 a0 = *(const short8*)(As + ((lane & 15)) * 32 + (lane >> 4) * 8);
    short8 a1 = *(const short8*)(As + (16 + (lane & 15)) * 32 + (lane >> 4) * 8);
#pragma unroll
    for (int qq = 0; qq < 2; ++qq) {
      short8 bf_ = *(const short8*)(Bs + ((w * 2 + qq) * 16 + (lane & 15)) * 32 + (lane >> 4) * 8);
      acc[0][qq] = __builtin_amdgcn_mfma_f32_16x16x32_bf16(a0, bf_, acc[0][qq], 0, 0, 0);
      acc[1][qq] = __builtin_amdgcn_mfma_f32_16x16x32_bf16(a1, bf_, acc[1][qq], 0, 0, 0);
    }
  }
#pragma unroll
  for (int mt = 0; mt < 2; ++mt)
#pragma unroll
    for (int qq = 0; qq < 2; ++qq)
#pragma unroll
      for (int reg = 0; reg < 4; ++reg) {
        int t_ = mt * 16 + (lane >> 4) * 4 + reg;
        int c = n0 + (w * 2 + qq) * 16 + (lane & 15);
        if (c < Nvalid) {
          float v = acc[mt][qq][reg];
          catall[(size_t)(t_ * 32 + b) * 2144 + catOff + c] = f2bf(v);
          atomicAdd(&gaccs[t_], v * Wg[wgOff + c]);
        }
      }
  __syncthreads();
  if (tid < 32) atomicAdd(&cp_acc[tid * 32 + b], gaccs[tid]);
}

// --------------------------- cat h/ue + gate finish ------------------------
__global__ __launch_bounds__(256) void k_catgate(const us* __restrict__ hball,
                                                 const float* __restrict__ hfall,
                                                 const float* __restrict__ ue,
                                                 const float* __restrict__ Wg,
                                                 const float* __restrict__ cp_acc,
                                                 us* __restrict__ catall,
                                                 float* __restrict__ cp_all) {
  __shared__ float r4[4];
  int r = blockIdx.x, tid = threadIdx.x;
  int t = r >> 5, b = r & 31;
  us* row = catall + (size_t)r * 2144;
  const us* hb = hball + (size_t)(t + 1) * 16384 + b * 512;
  row[tid] = hb[tid];
  row[256 + tid] = hb[256 + tid];
  float gp = 0.f;
  for (int i = tid; i < 512; i += 256)
    gp += hfall[(size_t)t * 16384 + b * 512 + i] * Wg[1024 + i];
  for (int i = tid; i < 308; i += 256)
    row[1836 + i] = (i < 300) ? f2bf(ue[b * 300 + i]) : (us)0;
  float gtot = bsum256(gp, r4, tid);
  if (tid == 0) cp_all[r] = fsigmoid(gtot + cp_acc[r]);
}

// --------------------------- finalize --------------------------------------
__global__ __launch_bounds__(256) void k_finalize(float* __restrict__ out,
                                                  const float* __restrict__ rowsum,
                                                  const float* __restrict__ cp_all,
                                                  const float* __restrict__ au_all,
                                                  const int* __restrict__ sv) {
  int r = blockIdx.x;  // t*32+b
  int t = threadIdx.x;
  int b = r & 31, tt = r >> 5;
  float cp = cp_all[r];
  float scale = (1.f - cp) / rowsum[r];
  float* base = out + (size_t)(b * 32 + tt) * 50200;
  float4* b4 = (float4*)base;
  for (int i = t; i < 12550; i += 256) {
    if (i < 12500) {
      float4 v = b4[i];
      v.x *= scale; v.y *= scale; v.z *= scale; v.w *= scale;
      b4[i] = v;
    } else {
      b4[i] = make_float4(0.f, 0.f, 0.f, 0.f);
    }
  }
  __syncthreads();
  if (t < 200) {
    int idx = sv[b * 200 + t];
    atomicAdd(base + idx, cp * au_all[(size_t)r * 200 + t]);
  }
}

// ---------------------------------------------------------------------------

extern "C" void kernel_launch(void* const* d_in, const int* in_sizes, int n_in,
                              void* d_out, int out_size, void* d_ws, size_t ws_size,
                              hipStream_t stream) {
  (void)in_sizes; (void)n_in; (void)out_size; (void)ws_size;
  const float* enc = (const float*)d_in[0];
  const float* hidden0 = (const float*)d_in[1];
  const float* user_embed = (const float*)d_in[2];
  const float* W_embed = (const float*)d_in[3];
  const float* W_ih = (const float*)d_in[4];
  const float* W_hh = (const float*)d_in[5];
  const float* b_ih = (const float*)d_in[6];
  const float* b_hh = (const float*)d_in[7];
  const float* Wk_c = (const float*)d_in[8];
  const float* bk_c = (const float*)d_in[9];
  const float* Wq_c = (const float*)d_in[10];
  const float* bq_c = (const float*)d_in[11];
  const float* we_c = (const float*)d_in[12];
  const float* be_c = (const float*)d_in[13];
  const float* Wk_u = (const float*)d_in[14];
  const float* bk_u = (const float*)d_in[15];
  const float* Wq_u = (const float*)d_in[16];
  const float* bq_u = (const float*)d_in[17];
  const float* we_u = (const float*)d_in[18];
  const float* be_u = (const float*)d_in[19];
  const float* Wc = (const float*)d_in[20];
  const float* Wg = (const float*)d_in[21];
  const float* bg = (const float*)d_in[22];
  const float* Wgen = (const float*)d_in[23];
  const int* src_mask = (const int*)d_in[24];
  const int* tgt = (const int*)d_in[25];
  const int* sv = (const int*)d_in[26];
  float* out = (float*)d_out;

  // ---------------- workspace layout (~121 MB, with unions) ----------------
  char* base = (char*)d_ws;
  size_t off = 0;
  auto take = [&](size_t bytes) {
    char* p = base + off;
    off += (bytes + 255) & ~(size_t)255;
    return p;
  };
  us* WT = (us*)take(50000ull * 512 * 2);                 // Wgen^T bf16
  char* R0 = take(32ull * 1024 * 416 * 2);                // encb -> encTp
  us* encb = (us*)R0;                                     // [12800][1024]
  us* encTp = (us*)R0;                                    // [b][1024][416]
  char* RCD = take(12800ull * 512 * 2 + 6400ull * 512 * 2);
  us* pkc = (us*)RCD;                                     // [12800][512]
  us* pku = (us*)(RCD + 12800ull * 512 * 2);              // [6400][512]
  us* AC = (us*)RCD;                                      // [32][32][416] (after scores)
  us* AU = (us*)(RCD + 860160);                           // [32][32][224]
  float* aual = (float*)(RCD + 860160 + 458752);          // [1024][200]
  us* catall = (us*)(RCD + 860160 + 458752 + 819200);     // [1024][2144]
  us* chb = (us*)(RCD + 860160 + 458752 + 819200 + 4390912);  // [1024][512]
  char* RU = take(6400ull * 320 * 2);                     // uve -> sc_enc/sc_usr
  us* uve = (us*)RU;
  float* sc_enc = (float*)RU;                             // [1024][400]
  float* sc_usr = (float*)(RU + 1024ull * 400 * 4);       // [1024][200]
  us* uveTp = (us*)take(32ull * 320 * 224 * 2);           // [b][320][224]
  char* RG = take(2700000);                               // WkcT|WihT|xe -> Qall
  us* WkcT = (us*)RG;                                     // [512][1024]
  us* WihT = (us*)(RG + 1048576);                         // [1536][320]
  us* xe = (us*)(RG + 1048576 + 983040);                  // [1024][320]
  us* Qall = (us*)RG;                                     // [1024][1024] (after gib)
  us* WkuT = (us*)take(512ull * 320 * 2);
  us* WqcuT = (us*)take(1024ull * 512 * 2);
  us* WcT = (us*)take(512ull * 2144 * 2);
  us* WhhF = (us*)take(1536ull * 512 * 2);                // fragment-packed Whh
  us* gib = (us*)take(1024ull * 1536 * 2);
  us* hball = (us*)take(33ull * 16384 * 2);
  float* hfall = (float*)take(32ull * 16384 * 4);
  float* bqcu = (float*)take(1024 * 4);
  float* cp_acc = (float*)take(1024 * 4);
  float* cp_all = (float*)take(1024 * 4);
  float* rsum = (float*)take(1024 * 4);
  int* arrive = (int*)take(32 * 4);

  // ---------------- precompute ----------------
  hipMemcpyAsync(bqcu, bq_c, 512 * 4, hipMemcpyDeviceToDevice, stream);
  hipMemcpyAsync(bqcu + 512, bq_u, 512 * 4, hipMemcpyDeviceToDevice, stream);
  hipMemsetAsync(rsum, 0, 1024 * 4, stream);
  hipMemsetAsync(arrive, 0, 32 * 4, stream);

  k_cast_f2b<<<2048, 256, 0, stream>>>(enc, encb, 3276800);
  k_cast_f2b<<<16, 256, 0, stream>>>(hidden0, hball, 4096);  // hball[0]
  k_tcastX<<<dim3(1563, 16, 1), 256, 0, stream>>>(Wgen, WT, 512, 50000, 512, 0, 0);
  k_tcastX<<<dim3(16, 32, 1), 256, 0, stream>>>(Wk_c, WkcT, 1024, 512, 1024, 0, 0);
  k_tcastX<<<dim3(16, 10, 1), 256, 0, stream>>>(Wk_u, WkuT, 300, 512, 320, 0, 0);
  k_tcastX<<<dim3(16, 16, 1), 256, 0, stream>>>(Wq_c, WqcuT, 512, 512, 512, 0, 0);
  k_tcastX<<<dim3(16, 16, 1), 256, 0, stream>>>(Wq_u, WqcuT + 512ull * 512, 512, 512, 512, 0, 0);
  k_tcastX<<<dim3(16, 67, 1), 256, 0, stream>>>(Wc, WcT, 2136, 512, 2144, 0, 0);
  k_castpad<<<1536, 64, 0, stream>>>(W_ih, WihT, 300, 320);
  k_fragpack<<<dim3(8, 12, 16), 64, 0, stream>>>(W_hh, WhhF);
  k_gather_xe<<<1024, 64, 0, stream>>>(W_embed, tgt, xe);
  k_gather_uve<<<6400, 64, 0, stream>>>(W_embed, sv, uve);

  // proj keys + gi (batched GEMMs)
  gemm_bt<0><<<200, 512, 0, stream>>>(encb, WkcT, 12800, 512, 1024, 4, bk_c, pkc, nullptr, nullptr);
  gemm_bt<0><<<100, 512, 0, stream>>>(uve, WkuT, 6400, 512, 320, 4, bk_u, pku, nullptr, nullptr);
  gemm_bt<0><<<48, 512, 0, stream>>>(xe, WihT, 1024, 1536, 320, 12, b_ih, gib, nullptr, nullptr);

  // transposes for ctx GEMMs (encTp overwrites encb AFTER pkc GEMM)
  k_tcastX<<<dim3(32, 13, 32), 256, 0, stream>>>(enc, encTp, 400, 1024, 416,
                                                 400ull * 1024, 1024ull * 416);
  k_tcastXb<<<dim3(10, 7, 32), 256, 0, stream>>>(uve, uveTp, 200, 320, 224,
                                                 200ull * 320, 320ull * 224);

  // ---------------- sequential GRU (8 blocks, flag barrier) ----------------
  GP gp;
  gp.frag = WhhF; gp.gib = gib; gp.bhh = b_hh; gp.hidden0 = hidden0;
  gp.hball = hball; gp.hfall = hfall; gp.arrive = arrive;
  k_gru<<<8, 768, 0, stream>>>(gp);

  // ---------------- batched attention + output ----------------
  gemm_bt<0><<<32, 512, 0, stream>>>(hball + 16384, WqcuT, 1024, 1024, 512, 8, bqcu,
                                     Qall, nullptr, nullptr);
  k_scores<<<2400, 256, 0, stream>>>(Qall, pkc, pku, we_c, be_c, we_u, be_u,
                                     src_mask, sc_enc, sc_usr);
  k_softmax<<<2048, 256, 0, stream>>>(sc_enc, sc_usr, bg, AC, AU, aual, cp_acc);
  k_ctx<<<dim3(8, 32), 256, 0, stream>>>(AC, encTp, Wg, catall, cp_acc,
                                         1024, 416, 512, 0, 1024);
  k_ctx<<<dim3(3, 32), 256, 0, stream>>>(AU, uveTp, Wg, catall, cp_acc,
                                         320, 224, 1536, 1536, 300);
  k_catgate<<<1024, 256, 0, stream>>>(hball, hfall, user_embed, Wg, cp_acc,
                                      catall, cp_all);
  gemm_bt<2><<<16, 512, 0, stream>>>(catall, WcT, 1024, 512, 2144, 4, nullptr, chb,
                                     nullptr, nullptr);
  gemm_bt<1><<<4 * 391, 512, 0, stream>>>(chb, WT, 1024, 50000, 512, 391, nullptr,
                                          nullptr, out, rsum);
  k_finalize<<<1024, 256, 0, stream>>>(out, rsum, cp_all, aual, sv);
}

// Round 5
// 787.596 us; speedup vs baseline: 7.3092x; 1.1329x over previous
//
#include <hip/hip_runtime.h>

// ---------------------------------------------------------------------------
// Pointer-generator decoder. B=32 S=400 H=512 E=300 Vs=200 T=32 EN=50000 V=50200
// Round 5: fast-tanh scores (4 s/wave), medium-tile GEMM for ch/Qall/gib,
// optional bf16-exp vocab tail (ws_size-guarded). GRU unchanged from round 4.
// ---------------------------------------------------------------------------

typedef __attribute__((ext_vector_type(8))) short short8;
typedef __attribute__((ext_vector_type(4))) float f32x4;
typedef unsigned short us;

__device__ __forceinline__ float bf2f(us u) {
  return __uint_as_float(((unsigned)u) << 16);
}
__device__ __forceinline__ us f2bf(float f) {
  unsigned x = __float_as_uint(f);
  unsigned r = x + 0x7fffu + ((x >> 16) & 1u);
  return (us)(r >> 16);
}
__device__ __forceinline__ float fsigmoid(float x) { return 1.f / (1.f + __expf(-x)); }
__device__ __forceinline__ float ftanh(float x) {
  float t = __expf(-2.f * fabsf(x));
  float r = (1.f - t) / (1.f + t);
  return x >= 0.f ? r : -r;
}
// fast tanh: u = e^{-2|x|} <= 1 (no overflow); rcp is v_rcp_f32 (~1 ulp)
__device__ __forceinline__ float ftanh_fast(float x) {
  float u = __expf(-2.f * fabsf(x));
  float r = (1.f - u) * __builtin_amdgcn_rcpf(1.f + u);
  return copysignf(r, x);
}

// --------------------------- precompute kernels ----------------------------

__global__ __launch_bounds__(256) void k_cast_f2b(const float* __restrict__ src,
                                                  us* __restrict__ dst, int n4) {
  int stride = gridDim.x * blockDim.x;
  for (int i = blockIdx.x * blockDim.x + threadIdx.x; i < n4; i += stride) {
    float4 v = ((const float4*)src)[i];
    ushort4 o;
    o.x = f2bf(v.x); o.y = f2bf(v.y); o.z = f2bf(v.z); o.w = f2bf(v.w);
    ((ushort4*)dst)[i] = o;
  }
}

// transpose + cast (f32 src): src [R][C] -> dst [C][Rpad] bf16, batched over z
__global__ __launch_bounds__(256) void k_tcastX(const float* __restrict__ src0,
                                                us* __restrict__ dst0,
                                                int R, int C, int Rpad,
                                                size_t srcB, size_t dstB) {
  __shared__ float tile[32][33];
  const float* src = src0 + (size_t)blockIdx.z * srcB;
  us* dst = dst0 + (size_t)blockIdx.z * dstB;
  int c0 = blockIdx.x * 32, r0 = blockIdx.y * 32;
  int tx = threadIdx.x & 31, ty = threadIdx.x >> 5;
#pragma unroll
  for (int i = 0; i < 4; ++i) {
    int r = r0 + ty + i * 8, c = c0 + tx;
    tile[ty + i * 8][tx] = (r < R && c < C) ? src[(size_t)r * C + c] : 0.f;
  }
  __syncthreads();
#pragma unroll
  for (int i = 0; i < 4; ++i) {
    int c = c0 + ty + i * 8, rr = r0 + tx;
    if (c < C && rr < Rpad) dst[(size_t)c * Rpad + rr] = f2bf(tile[tx][ty + i * 8]);
  }
}

// transpose (bf16 src): src [R][C] bf16 -> dst [C][Rpad] bf16, batched over z
__global__ __launch_bounds__(256) void k_tcastXb(const us* __restrict__ src0,
                                                 us* __restrict__ dst0,
                                                 int R, int C, int Rpad,
                                                 size_t srcB, size_t dstB) {
  __shared__ us tile[32][33];
  const us* src = src0 + (size_t)blockIdx.z * srcB;
  us* dst = dst0 + (size_t)blockIdx.z * dstB;
  int c0 = blockIdx.x * 32, r0 = blockIdx.y * 32;
  int tx = threadIdx.x & 31, ty = threadIdx.x >> 5;
#pragma unroll
  for (int i = 0; i < 4; ++i) {
    int r = r0 + ty + i * 8, c = c0 + tx;
    tile[ty + i * 8][tx] = (r < R && c < C) ? src[(size_t)r * C + c] : (us)0;
  }
  __syncthreads();
#pragma unroll
  for (int i = 0; i < 4; ++i) {
    int c = c0 + ty + i * 8, rr = r0 + tx;
    if (c < C && rr < Rpad) dst[(size_t)c * Rpad + rr] = tile[tx][ty + i * 8];
  }
}

__global__ __launch_bounds__(64) void k_castpad(const float* __restrict__ src,
                                                us* __restrict__ dst,
                                                int C, int Cpad) {
  int row = blockIdx.x;
  for (int k = threadIdx.x; k < Cpad; k += 64)
    dst[(size_t)row * Cpad + k] = (k < C) ? f2bf(src[(size_t)row * C + k]) : (us)0;
}

__global__ __launch_bounds__(64) void k_gather_xe(const float* __restrict__ W_embed,
                                                  const int* __restrict__ tgt,
                                                  us* __restrict__ xe) {
  int r = blockIdx.x;
  int t = r >> 5, b = r & 31;
  int tok = (t == 0) ? 1 : tgt[b * 32 + (t - 1)];
  const float* src = W_embed + (size_t)tok * 300;
  for (int k = threadIdx.x; k < 320; k += 64)
    xe[(size_t)r * 320 + k] = (k < 300) ? f2bf(src[k]) : (us)0;
}

__global__ __launch_bounds__(64) void k_gather_uve(const float* __restrict__ W_embed,
                                                   const int* __restrict__ sv,
                                                   us* __restrict__ uve) {
  int row = blockIdx.x;  // b*200+v
  int tok = sv[row];
  const float* src = W_embed + (size_t)tok * 300;
  for (int k = threadIdx.x; k < 320; k += 64)
    uve[(size_t)row * 320 + k] = (k < 300) ? f2bf(src[k]) : (us)0;
}

// pack Whh [1536][512] f32 into per-block MFMA B-fragment order (bf16)
__global__ __launch_bounds__(64) void k_fragpack(const float* __restrict__ W,
                                                 us* __restrict__ F) {
  int q = blockIdx.x, lt = blockIdx.y, kt = blockIdx.z, l = threadIdx.x;
  int localrow = lt * 16 + (l & 15);
  int g = localrow >> 6, jj = localrow & 63;
  const float* src = W + (size_t)(g * 512 + q * 64 + jj) * 512 + kt * 32 + (l >> 4) * 8;
  us* dst = F + (((size_t)(q * 12 + lt) * 16 + kt) * 64 + l) * 8;
#pragma unroll
  for (int i = 0; i < 8; ++i) dst[i] = f2bf(src[i]);
}

// --------------------------- big MFMA GEMM ---------------------------------
// MODE 0: out bf16 = A@B + bias
// MODE 1: out fp32 exp(logit) -> outF[(r&31)*32+(r>>5)][c] of [1024][50200] + rowsum
// MODE 3: out bf16 exp(logit) -> outB (same row mapping, stride 50200) + rowsum
template <int MODE>
__global__ __launch_bounds__(512) void gemm_bt(const us* __restrict__ A,
                                               const us* __restrict__ BT,
                                               int M, int N, int K, int Ntiles,
                                               const float* __restrict__ bias,
                                               us* __restrict__ outB,
                                               float* __restrict__ outF,
                                               float* __restrict__ rowsum) {
  __shared__ us As[256 * 32];
  __shared__ us Bs[128 * 32];
  __shared__ float rs[256];
  const int tid = threadIdx.x;
  const int lane = tid & 63, wid = tid >> 6;
  const int wr = wid >> 1, wc = wid & 1;
  const int bx = blockIdx.x;
  const int mt = bx / Ntiles, nt = bx - mt * Ntiles;
  const int m0 = mt * 256, n0 = nt * 128;
  f32x4 acc[4][4] = {};
  for (int kk = 0; kk < K; kk += 32) {
    uint4 av0, av1, bv;
    {
      int c = tid, row = c >> 2, c8 = (c & 3) * 8;
      av0 = *(const uint4*)(A + (size_t)(m0 + row) * K + kk + c8);
      c = tid + 512; row = c >> 2; c8 = (c & 3) * 8;
      av1 = *(const uint4*)(A + (size_t)(m0 + row) * K + kk + c8);
      c = tid; row = c >> 2; c8 = (c & 3) * 8;
      int nr = n0 + row; if (nr > N - 1) nr = N - 1;
      bv = *(const uint4*)(BT + (size_t)nr * K + kk + c8);
    }
    __syncthreads();
    ((uint4*)As)[tid] = av0;
    ((uint4*)As)[tid + 512] = av1;
    ((uint4*)Bs)[tid] = bv;
    __syncthreads();
    short8 af[4], bfr[4];
#pragma unroll
    for (int m = 0; m < 4; ++m)
      af[m] = *(const short8*)(As + (wr * 64 + m * 16 + (lane & 15)) * 32 + (lane >> 4) * 8);
#pragma unroll
    for (int n = 0; n < 4; ++n)
      bfr[n] = *(const short8*)(Bs + (wc * 64 + n * 16 + (lane & 15)) * 32 + (lane >> 4) * 8);
#pragma unroll
    for (int m = 0; m < 4; ++m)
#pragma unroll
      for (int n = 0; n < 4; ++n)
        acc[m][n] = __builtin_amdgcn_mfma_f32_16x16x32_bf16(af[m], bfr[n], acc[m][n], 0, 0, 0);
  }
  if (MODE == 0) {
#pragma unroll
    for (int m = 0; m < 4; ++m)
#pragma unroll
      for (int n = 0; n < 4; ++n)
#pragma unroll
        for (int reg = 0; reg < 4; ++reg) {
          int r = m0 + wr * 64 + m * 16 + (lane >> 4) * 4 + reg;
          int c = n0 + wc * 64 + n * 16 + (lane & 15);
          outB[(size_t)r * N + c] = f2bf(acc[m][n][reg] + bias[c]);
        }
  } else {
    if (tid < 256) rs[tid] = 0.f;
    __syncthreads();
#pragma unroll
    for (int m = 0; m < 4; ++m) {
#pragma unroll
      for (int reg = 0; reg < 4; ++reg) {
        int rloc = wr * 64 + m * 16 + (lane >> 4) * 4 + reg;
        int r = m0 + rloc;
        size_t obase = (size_t)((r & 31) * 32 + (r >> 5)) * 50200;
        float s = 0.f;
#pragma unroll
        for (int n = 0; n < 4; ++n) {
          int c = n0 + wc * 64 + n * 16 + (lane & 15);
          if (c < N) {
            float e = __expf(acc[m][n][reg]);
            if (MODE == 1) outF[obase + c] = e;
            else outB[obase + c] = f2bf(e);
            s += e;
          }
        }
        s += __shfl_xor(s, 1, 64); s += __shfl_xor(s, 2, 64);
        s += __shfl_xor(s, 4, 64); s += __shfl_xor(s, 8, 64);
        if ((lane & 15) == 0) atomicAdd(&rs[rloc], s);
      }
    }
    __syncthreads();
    if (tid < 256) atomicAdd(&rowsum[m0 + tid], rs[tid]);
  }
}

// --------------------------- medium MFMA GEMM (BM=64, BN=128) --------------
// 256 threads / 4 waves; wave w owns 32 N-cols. MODE 0: +bias -> bf16;
// MODE 2: tanh -> bf16. Requires 64|M, 128|N, 32|K.
template <int MODE>
__global__ __launch_bounds__(256) void gemm_med(const us* __restrict__ A,
                                                const us* __restrict__ BT,
                                                int M, int N, int K, int Ntiles,
                                                const float* __restrict__ bias,
                                                us* __restrict__ outB) {
  __shared__ us As[64 * 32];
  __shared__ us Bs[128 * 32];
  const int tid = threadIdx.x, lane = tid & 63, w = tid >> 6;
  const int bx = blockIdx.x;
  const int mt = bx / Ntiles, nt = bx - mt * Ntiles;
  const int m0 = mt * 64, n0 = nt * 128;
  f32x4 acc[4][2] = {};
  for (int kk = 0; kk < K; kk += 32) {
    uint4 av, bv0, bv1;
    av = *(const uint4*)(A + (size_t)(m0 + (tid >> 2)) * K + kk + (tid & 3) * 8);
    {
      int i0 = tid * 2, i1 = tid * 2 + 1;
      bv0 = *(const uint4*)(BT + (size_t)(n0 + (i0 >> 2)) * K + kk + (i0 & 3) * 8);
      bv1 = *(const uint4*)(BT + (size_t)(n0 + (i1 >> 2)) * K + kk + (i1 & 3) * 8);
    }
    __syncthreads();
    ((uint4*)As)[tid] = av;
    ((uint4*)Bs)[tid * 2] = bv0;
    ((uint4*)Bs)[tid * 2 + 1] = bv1;
    __syncthreads();
    short8 af[4], bf0, bf1;
#pragma unroll
    for (int m = 0; m < 4; ++m)
      af[m] = *(const short8*)(As + (m * 16 + (lane & 15)) * 32 + (lane >> 4) * 8);
    bf0 = *(const short8*)(Bs + ((w * 2 + 0) * 16 + (lane & 15)) * 32 + (lane >> 4) * 8);
    bf1 = *(const short8*)(Bs + ((w * 2 + 1) * 16 + (lane & 15)) * 32 + (lane >> 4) * 8);
#pragma unroll
    for (int m = 0; m < 4; ++m) {
      acc[m][0] = __builtin_amdgcn_mfma_f32_16x16x32_bf16(af[m], bf0, acc[m][0], 0, 0, 0);
      acc[m][1] = __builtin_amdgcn_mfma_f32_16x16x32_bf16(af[m], bf1, acc[m][1], 0, 0, 0);
    }
  }
#pragma unroll
  for (int m = 0; m < 4; ++m)
#pragma unroll
    for (int q = 0; q < 2; ++q)
#pragma unroll
      for (int reg = 0; reg < 4; ++reg) {
        int r = m0 + m * 16 + (lane >> 4) * 4 + reg;
        int c = n0 + (w * 2 + q) * 16 + (lane & 15);
        float v = acc[m][q][reg];
        if (MODE == 0) v += bias[c];
        else v = ftanh_fast(v);
        outB[(size_t)r * N + c] = f2bf(v);
      }
}

// --------------------------- GRU: 8 blocks, weights in registers -----------
struct GP {
  const us* frag; const us* gib; const float* bhh; const float* hidden0;
  us* hball;    // [33][32][512] bf16
  float* hfall; // [32][32][512] f32
  int* arrive;  // [32]
};

__global__ __launch_bounds__(768, 1) void k_gru(GP P) {
  const int q = blockIdx.x;
  const int tid = threadIdx.x;
  const int lane = tid & 63, w = tid >> 6;
  __shared__ us hs[32 * 512];
  __shared__ float gh[192 * 33];
  short8 bfr[16];
  {
    const us* fb = P.frag + (((size_t)(q * 12 + w) * 16) * 64 + lane) * 8;
#pragma unroll
    for (int kt = 0; kt < 16; ++kt) bfr[kt] = *(const short8*)(fb + (size_t)kt * 512);
  }
  float hprev[3];
#pragma unroll
  for (int s = 0; s < 3; ++s) {
    int i = tid + s * 768;
    if (i < 2048) {
      int b = i >> 6, jj = i & 63;
      hprev[s] = P.hidden0[b * 512 + q * 64 + jj];
    }
  }
  const int sw = (lane & 7) << 3;
  for (int t = 0; t < 32; ++t) {
    if (t > 0) {
      if (tid == 0) {
        while (__hip_atomic_load(P.arrive + (t - 1), __ATOMIC_ACQUIRE,
                                 __HIP_MEMORY_SCOPE_AGENT) < 8) {
          __builtin_amdgcn_s_sleep(1);
        }
      }
      __syncthreads();
    }
    const us* hp = P.hball + (size_t)t * 16384;
    for (int i = tid; i < 2048; i += 768)
      ((uint4*)hs)[i ^ ((i >> 6) & 7)] = *(const uint4*)(hp + i * 8);
    __syncthreads();
    f32x4 acc0 = {}, acc1 = {};
#pragma unroll
    for (int kt = 0; kt < 16; ++kt) {
      int base0 = ((lane & 15) * 512 + kt * 32 + (lane >> 4) * 8) ^ sw;
      int base1 = (((lane & 15) + 16) * 512 + kt * 32 + (lane >> 4) * 8) ^ sw;
      short8 a0 = *(const short8*)(hs + base0);
      short8 a1 = *(const short8*)(hs + base1);
      acc0 = __builtin_amdgcn_mfma_f32_16x16x32_bf16(a0, bfr[kt], acc0, 0, 0, 0);
      acc1 = __builtin_amdgcn_mfma_f32_16x16x32_bf16(a1, bfr[kt], acc1, 0, 0, 0);
    }
    {
      int col = w * 16 + (lane & 15);
#pragma unroll
      for (int reg = 0; reg < 4; ++reg) {
        gh[col * 33 + ((lane >> 4) * 4 + reg)] = acc0[reg];
        gh[col * 33 + (16 + (lane >> 4) * 4 + reg)] = acc1[reg];
      }
    }
    __syncthreads();
    us* hbn = P.hball + (size_t)(t + 1) * 16384;
    float* hfn = P.hfall + (size_t)t * 16384;
#pragma unroll
    for (int s = 0; s < 3; ++s) {
      int i = tid + s * 768;
      if (i < 2048) {
        int b = i >> 6, jj = i & 63;
        int j = q * 64 + jj;
        float g0 = gh[jj * 33 + b] + P.bhh[j];
        float g1 = gh[(64 + jj) * 33 + b] + P.bhh[512 + j];
        float g2 = gh[(128 + jj) * 33 + b] + P.bhh[1024 + j];
        size_t gbase = (size_t)(t * 32 + b) * 1536;
        float r_ = fsigmoid(bf2f(P.gib[gbase + j]) + g0);
        float z_ = fsigmoid(bf2f(P.gib[gbase + 512 + j]) + g1);
        float n_ = ftanh(bf2f(P.gib[gbase + 1024 + j]) + r_ * g2);
        float hv = (1.f - z_) * n_ + z_ * hprev[s];
        hprev[s] = hv;
        hbn[b * 512 + j] = f2bf(hv);
        hfn[b * 512 + j] = hv;
      }
    }
    __syncthreads();
    if (tid == 0)
      __hip_atomic_fetch_add(P.arrive + t, 1, __ATOMIC_RELEASE,
                             __HIP_MEMORY_SCOPE_AGENT);
  }
}

// --------------------------- batched scores (v2) ---------------------------
// 1216 blocks: enc 800 (32 b x 25 chunks of 16 s), usr 416 (32 b x 13 x 16).
// Per block: stage q (32 t x 512 d bf16 = 32 KB); wave handles 4 s, loops t.
__global__ __launch_bounds__(256) void k_scores(const us* __restrict__ Qall,
                                                const us* __restrict__ pkc,
                                                const us* __restrict__ pku,
                                                const float* __restrict__ wec,
                                                const float* __restrict__ bec,
                                                const float* __restrict__ weu,
                                                const float* __restrict__ beu,
                                                const int* __restrict__ src_mask,
                                                float* __restrict__ sc_enc,
                                                float* __restrict__ sc_usr) {
  __shared__ us q[32 * 512];
  const int bid = blockIdx.x;
  const bool enc = bid < 800;
  int b, s0, qoff, S;
  if (enc) { b = bid / 25; s0 = (bid % 25) * 16; qoff = 0; S = 400; }
  else { int j = bid - 800; b = j / 13; s0 = (j % 13) * 16; qoff = 512; S = 200; }
  for (int i = threadIdx.x; i < 2048; i += 256) {
    int tt = i >> 6, c8 = (i & 63) * 8;
    ((uint4*)q)[i] = *(const uint4*)(Qall + (size_t)(tt * 32 + b) * 1024 + qoff + c8);
  }
  const int w = threadIdx.x >> 6, lane = threadIdx.x & 63;
  const int d0 = lane * 8;
  const float* we = enc ? wec : weu;
  float wef[8];
  {
    float4 w0 = *(const float4*)(we + d0);
    float4 w1 = *(const float4*)(we + d0 + 4);
    wef[0] = w0.x; wef[1] = w0.y; wef[2] = w0.z; wef[3] = w0.w;
    wef[4] = w1.x; wef[5] = w1.y; wef[6] = w1.z; wef[7] = w1.w;
  }
  const float bias = enc ? bec[0] : beu[0];
  float pkf[4][8];
  int ss[4], validv[4], maskedv[4];
#pragma unroll
  for (int si = 0; si < 4; ++si) {
    int s = s0 + w * 4 + si;
    validv[si] = (s < S);
    int sc = validv[si] ? s : (S - 1);
    ss[si] = sc;
    const us* pk = enc ? pkc + ((size_t)b * 400 + sc) * 512
                       : pku + ((size_t)b * 200 + sc) * 512;
    uint4 pkv = *(const uint4*)(pk + d0);
    pkf[si][0] = bf2f((us)(pkv.x & 0xffff)); pkf[si][1] = bf2f((us)(pkv.x >> 16));
    pkf[si][2] = bf2f((us)(pkv.y & 0xffff)); pkf[si][3] = bf2f((us)(pkv.y >> 16));
    pkf[si][4] = bf2f((us)(pkv.z & 0xffff)); pkf[si][5] = bf2f((us)(pkv.z >> 16));
    pkf[si][6] = bf2f((us)(pkv.w & 0xffff)); pkf[si][7] = bf2f((us)(pkv.w >> 16));
    maskedv[si] = enc ? (src_mask[b * 400 + sc] == 0) : 0;
  }
  __syncthreads();
  for (int t = 0; t < 32; ++t) {
    short8 qv = *(const short8*)(q + t * 512 + d0);
    float qf[8];
#pragma unroll
    for (int d = 0; d < 8; ++d) qf[d] = bf2f((us)qv[d]);
#pragma unroll
    for (int si = 0; si < 4; ++si) {
      float a = 0.f;
#pragma unroll
      for (int d = 0; d < 8; ++d) {
        float x = qf[d] + pkf[si][d];
        float u = __expf(-2.f * fabsf(x));
        float r2 = (1.f - u) * __builtin_amdgcn_rcpf(1.f + u);
        a = fmaf(copysignf(r2, x), wef[d], a);
      }
#pragma unroll
      for (int m = 1; m < 64; m <<= 1) a += __shfl_xor(a, m, 64);
      if (lane == 0 && validv[si]) {
        float v = a + bias;
        if (enc) sc_enc[(size_t)(t * 32 + b) * 400 + ss[si]] = maskedv[si] ? -1e9f : v;
        else sc_usr[(size_t)(t * 32 + b) * 200 + ss[si]] = v;
      }
    }
  }
}

// --------------------------- batched softmax -------------------------------
__device__ __forceinline__ float bmax256(float v, float* r4, int tid) {
#pragma unroll
  for (int m = 1; m < 64; m <<= 1) v = fmaxf(v, __shfl_xor(v, m, 64));
  if ((tid & 63) == 0) r4[tid >> 6] = v;
  __syncthreads();
  float x = fmaxf(fmaxf(r4[0], r4[1]), fmaxf(r4[2], r4[3]));
  __syncthreads();
  return x;
}
__device__ __forceinline__ float bsum256(float v, float* r4, int tid) {
#pragma unroll
  for (int m = 1; m < 64; m <<= 1) v += __shfl_xor(v, m, 64);
  if ((tid & 63) == 0) r4[tid >> 6] = v;
  __syncthreads();
  float x = r4[0] + r4[1] + r4[2] + r4[3];
  __syncthreads();
  return x;
}

__global__ __launch_bounds__(256) void k_softmax(const float* __restrict__ sc_enc,
                                                 const float* __restrict__ sc_usr,
                                                 const float* __restrict__ bg,
                                                 us* __restrict__ AC,
                                                 us* __restrict__ AU,
                                                 float* __restrict__ aual,
                                                 float* __restrict__ cp_acc) {
  __shared__ float r4[4];
  int r = blockIdx.x, tid = threadIdx.x;
  if (r < 1024) {
    int t = r >> 5, b = r & 31;
    float v0 = (tid < 400) ? sc_enc[(size_t)r * 400 + tid] : -3e38f;
    float v1 = (tid + 256 < 400) ? sc_enc[(size_t)r * 400 + tid + 256] : -3e38f;
    float mx = bmax256(fmaxf(v0, v1), r4, tid);
    float e0 = (tid < 400) ? __expf(v0 - mx) : 0.f;
    float e1 = (tid + 256 < 400) ? __expf(v1 - mx) : 0.f;
    float inv = 1.f / bsum256(e0 + e1, r4, tid);
    us* ACb = AC + (size_t)(b * 32 + t) * 416;
    if (tid < 400) ACb[tid] = f2bf(e0 * inv);
    int s2 = tid + 256;
    if (s2 < 400) ACb[s2] = f2bf(e1 * inv);
    else if (s2 < 416) ACb[s2] = 0;
    if (tid == 0) cp_acc[r] = bg[0];
  } else {
    int rr = r - 1024;
    int t = rr >> 5, b = rr & 31;
    float v0 = (tid < 200) ? sc_usr[(size_t)rr * 200 + tid] : -3e38f;
    float mx = bmax256(v0, r4, tid);
    float e0 = (tid < 200) ? __expf(v0 - mx) : 0.f;
    float inv = 1.f / bsum256(e0, r4, tid);
    us* AUb = AU + (size_t)(b * 32 + t) * 224;
    if (tid < 200) {
      float a = e0 * inv;
      AUb[tid] = f2bf(a);
      aual[(size_t)rr * 200 + tid] = a;
    } else if (tid < 224) {
      AUb[tid] = 0;
    }
  }
}

// --------------------------- batched ctx GEMM ------------------------------
__global__ __launch_bounds__(256) void k_ctx(const us* __restrict__ A,
                                             const us* __restrict__ BT,
                                             const float* __restrict__ Wg,
                                             us* __restrict__ catall,
                                             float* __restrict__ cp_acc,
                                             int N, int Kp, int catOff, int wgOff,
                                             int Nvalid) {
  __shared__ us As[32 * 32];
  __shared__ us Bs[128 * 32];
  __shared__ float gaccs[32];
  const int b = blockIdx.y, n0 = blockIdx.x * 128;
  const us* Ab = A + (size_t)b * 32 * Kp;
  const us* Bb = BT + (size_t)b * N * Kp;
  const int tid = threadIdx.x, lane = tid & 63, w = tid >> 6;
  if (tid < 32) gaccs[tid] = 0.f;
  f32x4 acc[2][2] = {};
  for (int kk = 0; kk < Kp; kk += 32) {
    uint4 av, bv0, bv1;
    if (tid < 128) av = *(const uint4*)(Ab + (size_t)(tid >> 2) * Kp + kk + (tid & 3) * 8);
    {
      int i0 = tid * 2, row0 = i0 >> 2, c0 = (i0 & 3) * 8;
      int i1 = tid * 2 + 1, row1 = i1 >> 2, c1 = (i1 & 3) * 8;
      int nr0 = n0 + row0; if (nr0 > N - 1) nr0 = N - 1;
      int nr1 = n0 + row1; if (nr1 > N - 1) nr1 = N - 1;
      bv0 = *(const uint4*)(Bb + (size_t)nr0 * Kp + kk + c0);
      bv1 = *(const uint4*)(Bb + (size_t)nr1 * Kp + kk + c1);
    }
    __syncthreads();
    if (tid < 128) ((uint4*)As)[tid] = av;
    ((uint4*)Bs)[tid * 2] = bv0;
    ((uint4*)Bs)[tid * 2 + 1] = bv1;
    __syncthreads();
    short8 a0 = *(const short8*)(As + ((lane & 15)) * 32 + (lane >> 4) * 8);
    short8 a1 = *(const short8*)(As + (16 + (lane & 15)) * 32 + (lane >> 4) * 8);
#pragma unroll
    for (int qq = 0; qq < 2; ++qq) {
      short8 bf_ = *(const short8*)(Bs + ((w * 2 + qq) * 16 + (lane & 15)) * 32 + (lane >> 4) * 8);
      acc[0][qq] = __builtin_amdgcn_mfma_f32_16x16x32_bf16(a0, bf_, acc[0][qq], 0, 0, 0);
      acc[1][qq] = __builtin_amdgcn_mfma_f32_16x16x32_bf16(a1, bf_, acc[1][qq], 0, 0, 0);
    }
  }
#pragma unroll
  for (int mt = 0; mt < 2; ++mt)
#pragma unroll
    for (int qq = 0; qq < 2; ++qq)
#pragma unroll
      for (int reg = 0; reg < 4; ++reg) {
        int t_ = mt * 16 + (lane >> 4) * 4 + reg;
        int c = n0 + (w * 2 + qq) * 16 + (lane & 15);
        if (c < Nvalid) {
          float v = acc[mt][qq][reg];
          catall[(size_t)(t_ * 32 + b) * 2144 + catOff + c] = f2bf(v);
          atomicAdd(&gaccs[t_], v * Wg[wgOff + c]);
        }
      }
  __syncthreads();
  if (tid < 32) atomicAdd(&cp_acc[tid * 32 + b], gaccs[tid]);
}

// --------------------------- cat h/ue + gate finish ------------------------
__global__ __launch_bounds__(256) void k_catgate(const us* __restrict__ hball,
                                                 const float* __restrict__ hfall,
                                                 const float* __restrict__ ue,
                                                 const float* __restrict__ Wg,
                                                 const float* __restrict__ cp_acc,
                                                 us* __restrict__ catall,
                                                 float* __restrict__ cp_all) {
  __shared__ float r4[4];
  int r = blockIdx.x, tid = threadIdx.x;
  int t = r >> 5, b = r & 31;
  us* row = catall + (size_t)r * 2144;
  const us* hb = hball + (size_t)(t + 1) * 16384 + b * 512;
  row[tid] = hb[tid];
  row[256 + tid] = hb[256 + tid];
  float gp = 0.f;
  for (int i = tid; i < 512; i += 256)
    gp += hfall[(size_t)t * 16384 + b * 512 + i] * Wg[1024 + i];
  for (int i = tid; i < 308; i += 256)
    row[1836 + i] = (i < 300) ? f2bf(ue[b * 300 + i]) : (us)0;
  float gtot = bsum256(gp, r4, tid);
  if (tid == 0) cp_all[r] = fsigmoid(gtot + cp_acc[r]);
}

// --------------------------- finalize (f32 exp path) -----------------------
__global__ __launch_bounds__(256) void k_finalize(float* __restrict__ out,
                                                  const float* __restrict__ rowsum,
                                                  const float* __restrict__ cp_all,
                                                  const float* __restrict__ au_all,
                                                  const int* __restrict__ sv) {
  int r = blockIdx.x;  // t*32+b
  int t = threadIdx.x;
  int b = r & 31, tt = r >> 5;
  float cp = cp_all[r];
  float scale = (1.f - cp) / rowsum[r];
  float* base = out + (size_t)(b * 32 + tt) * 50200;
  float4* b4 = (float4*)base;
  for (int i = t; i < 12550; i += 256) {
    if (i < 12500) {
      float4 v = b4[i];
      v.x *= scale; v.y *= scale; v.z *= scale; v.w *= scale;
      b4[i] = v;
    } else {
      b4[i] = make_float4(0.f, 0.f, 0.f, 0.f);
    }
  }
  __syncthreads();
  if (t < 200) {
    int idx = sv[b * 200 + t];
    atomicAdd(base + idx, cp * au_all[(size_t)r * 200 + t]);
  }
}

// --------------------------- finalize (bf16 exp path) ----------------------
__global__ __launch_bounds__(256) void k_finalize2(const us* __restrict__ expb,
                                                   const float* __restrict__ rowsum,
                                                   const float* __restrict__ cp_all,
                                                   const float* __restrict__ au_all,
                                                   const int* __restrict__ sv,
                                                   float* __restrict__ out) {
  int r = blockIdx.x;  // t*32+b
  int t = threadIdx.x;
  int b = r & 31, tt = r >> 5;
  float cp = cp_all[r];
  float scale = (1.f - cp) / rowsum[r];
  size_t obase = (size_t)(b * 32 + tt) * 50200;
  const uint4* eb = (const uint4*)(expb + obase);
  float4* ob = (float4*)(out + obase);
  for (int i = t; i < 6275; i += 256) {
    float4 o0, o1;
    if (i < 6250) {
      uint4 ev = eb[i];
      o0.x = bf2f((us)(ev.x & 0xffff)) * scale; o0.y = bf2f((us)(ev.x >> 16)) * scale;
      o0.z = bf2f((us)(ev.y & 0xffff)) * scale; o0.w = bf2f((us)(ev.y >> 16)) * scale;
      o1.x = bf2f((us)(ev.z & 0xffff)) * scale; o1.y = bf2f((us)(ev.z >> 16)) * scale;
      o1.z = bf2f((us)(ev.w & 0xffff)) * scale; o1.w = bf2f((us)(ev.w >> 16)) * scale;
    } else {
      o0 = make_float4(0.f, 0.f, 0.f, 0.f);
      o1 = o0;
    }
    ob[i * 2] = o0;
    ob[i * 2 + 1] = o1;
  }
  __syncthreads();
  if (t < 200) {
    int idx = sv[b * 200 + t];
    atomicAdd(out + obase + idx, cp * au_all[(size_t)r * 200 + t]);
  }
}

// ---------------------------------------------------------------------------

extern "C" void kernel_launch(void* const* d_in, const int* in_sizes, int n_in,
                              void* d_out, int out_size, void* d_ws, size_t ws_size,
                              hipStream_t stream) {
  (void)in_sizes; (void)n_in; (void)out_size;
  const float* enc = (const float*)d_in[0];
  const float* hidden0 = (const float*)d_in[1];
  const float* user_embed = (const float*)d_in[2];
  const float* W_embed = (const float*)d_in[3];
  const float* W_ih = (const float*)d_in[4];
  const float* W_hh = (const float*)d_in[5];
  const float* b_ih = (const float*)d_in[6];
  const float* b_hh = (const float*)d_in[7];
  const float* Wk_c = (const float*)d_in[8];
  const float* bk_c = (const float*)d_in[9];
  const float* Wq_c = (const float*)d_in[10];
  const float* bq_c = (const float*)d_in[11];
  const float* we_c = (const float*)d_in[12];
  const float* be_c = (const float*)d_in[13];
  const float* Wk_u = (const float*)d_in[14];
  const float* bk_u = (const float*)d_in[15];
  const float* Wq_u = (const float*)d_in[16];
  const float* bq_u = (const float*)d_in[17];
  const float* we_u = (const float*)d_in[18];
  const float* be_u = (const float*)d_in[19];
  const float* Wc = (const float*)d_in[20];
  const float* Wg = (const float*)d_in[21];
  const float* bg = (const float*)d_in[22];
  const float* Wgen = (const float*)d_in[23];
  const int* src_mask = (const int*)d_in[24];
  const int* tgt = (const int*)d_in[25];
  const int* sv = (const int*)d_in[26];
  float* out = (float*)d_out;

  // ---------------- workspace layout (~121 MB base, with unions) -----------
  char* base = (char*)d_ws;
  size_t off = 0;
  auto take = [&](size_t bytes) {
    char* p = base + off;
    off += (bytes + 255) & ~(size_t)255;
    return p;
  };
  us* WT = (us*)take(50000ull * 512 * 2);
  char* R0 = take(32ull * 1024 * 416 * 2);                // encb -> encTp
  us* encb = (us*)R0;
  us* encTp = (us*)R0;
  char* RCD = take(12800ull * 512 * 2 + 6400ull * 512 * 2);
  us* pkc = (us*)RCD;
  us* pku = (us*)(RCD + 12800ull * 512 * 2);
  us* AC = (us*)RCD;
  us* AU = (us*)(RCD + 860160);
  float* aual = (float*)(RCD + 860160 + 458752);
  us* catall = (us*)(RCD + 860160 + 458752 + 819200);
  us* chb = (us*)(RCD + 860160 + 458752 + 819200 + 4390912);
  char* RU = take(6400ull * 320 * 2);                     // uve -> sc_enc/sc_usr
  us* uve = (us*)RU;
  float* sc_enc = (float*)RU;
  float* sc_usr = (float*)(RU + 1024ull * 400 * 4);
  us* uveTp = (us*)take(32ull * 320 * 224 * 2);
  char* RG = take(2700000);                               // WkcT|WihT|xe -> Qall
  us* WkcT = (us*)RG;
  us* WihT = (us*)(RG + 1048576);
  us* xe = (us*)(RG + 1048576 + 983040);
  us* Qall = (us*)RG;
  us* WkuT = (us*)take(512ull * 320 * 2);
  us* WqcuT = (us*)take(1024ull * 512 * 2);
  us* WcT = (us*)take(512ull * 2144 * 2);
  us* WhhF = (us*)take(1536ull * 512 * 2);
  us* gib = (us*)take(1024ull * 1536 * 2);
  us* hball = (us*)take(33ull * 16384 * 2);
  float* hfall = (float*)take(32ull * 16384 * 4);
  float* bqcu = (float*)take(1024 * 4);
  float* cp_acc = (float*)take(1024 * 4);
  float* cp_all = (float*)take(1024 * 4);
  float* rsum = (float*)take(1024 * 4);
  int* arrive = (int*)take(32 * 4);
  // optional bf16-exp buffer (103 MB) — only if workspace is large enough
  size_t expb_bytes = 1024ull * 50200 * 2;
  bool use_bf16exp = (ws_size >= off + expb_bytes + 256);
  us* expb = use_bf16exp ? (us*)take(expb_bytes) : nullptr;

  // ---------------- precompute ----------------
  hipMemcpyAsync(bqcu, bq_c, 512 * 4, hipMemcpyDeviceToDevice, stream);
  hipMemcpyAsync(bqcu + 512, bq_u, 512 * 4, hipMemcpyDeviceToDevice, stream);
  hipMemsetAsync(rsum, 0, 1024 * 4, stream);
  hipMemsetAsync(arrive, 0, 32 * 4, stream);

  k_cast_f2b<<<2048, 256, 0, stream>>>(enc, encb, 3276800);
  k_cast_f2b<<<16, 256, 0, stream>>>(hidden0, hball, 4096);  // hball[0]
  k_tcastX<<<dim3(1563, 16, 1), 256, 0, stream>>>(Wgen, WT, 512, 50000, 512, 0, 0);
  k_tcastX<<<dim3(16, 32, 1), 256, 0, stream>>>(Wk_c, WkcT, 1024, 512, 1024, 0, 0);
  k_tcastX<<<dim3(16, 10, 1), 256, 0, stream>>>(Wk_u, WkuT, 300, 512, 320, 0, 0);
  k_tcastX<<<dim3(16, 16, 1), 256, 0, stream>>>(Wq_c, WqcuT, 512, 512, 512, 0, 0);
  k_tcastX<<<dim3(16, 16, 1), 256, 0, stream>>>(Wq_u, WqcuT + 512ull * 512, 512, 512, 512, 0, 0);
  k_tcastX<<<dim3(16, 67, 1), 256, 0, stream>>>(Wc, WcT, 2136, 512, 2144, 0, 0);
  k_castpad<<<1536, 64, 0, stream>>>(W_ih, WihT, 300, 320);
  k_fragpack<<<dim3(8, 12, 16), 64, 0, stream>>>(W_hh, WhhF);
  k_gather_xe<<<1024, 64, 0, stream>>>(W_embed, tgt, xe);
  k_gather_uve<<<6400, 64, 0, stream>>>(W_embed, sv, uve);

  // proj keys + gi (batched GEMMs)
  gemm_bt<0><<<200, 512, 0, stream>>>(encb, WkcT, 12800, 512, 1024, 4, bk_c, pkc, nullptr, nullptr);
  gemm_bt<0><<<100, 512, 0, stream>>>(uve, WkuT, 6400, 512, 320, 4, bk_u, pku, nullptr, nullptr);
  gemm_med<0><<<192, 256, 0, stream>>>(xe, WihT, 1024, 1536, 320, 12, b_ih, gib);

  // transposes for ctx GEMMs (encTp overwrites encb AFTER pkc GEMM)
  k_tcastX<<<dim3(32, 13, 32), 256, 0, stream>>>(enc, encTp, 400, 1024, 416,
                                                 400ull * 1024, 1024ull * 416);
  k_tcastXb<<<dim3(10, 7, 32), 256, 0, stream>>>(uve, uveTp, 200, 320, 224,
                                                 200ull * 320, 320ull * 224);

  // ---------------- sequential GRU (8 blocks, flag barrier) ----------------
  GP gp;
  gp.frag = WhhF; gp.gib = gib; gp.bhh = b_hh; gp.hidden0 = hidden0;
  gp.hball = hball; gp.hfall = hfall; gp.arrive = arrive;
  k_gru<<<8, 768, 0, stream>>>(gp);

  // ---------------- batched attention + output ----------------
  gemm_med<0><<<128, 256, 0, stream>>>(hball + 16384, WqcuT, 1024, 1024, 512, 8,
                                       bqcu, Qall);
  k_scores<<<1216, 256, 0, stream>>>(Qall, pkc, pku, we_c, be_c, we_u, be_u,
                                     src_mask, sc_enc, sc_usr);
  k_softmax<<<2048, 256, 0, stream>>>(sc_enc, sc_usr, bg, AC, AU, aual, cp_acc);
  k_ctx<<<dim3(8, 32), 256, 0, stream>>>(AC, encTp, Wg, catall, cp_acc,
                                         1024, 416, 512, 0, 1024);
  k_ctx<<<dim3(3, 32), 256, 0, stream>>>(AU, uveTp, Wg, catall, cp_acc,
                                         320, 224, 1536, 1536, 300);
  k_catgate<<<1024, 256, 0, stream>>>(hball, hfall, user_embed, Wg, cp_acc,
                                      catall, cp_all);
  gemm_med<2><<<64, 256, 0, stream>>>(catall, WcT, 1024, 512, 2144, 4, nullptr, chb);
  if (use_bf16exp) {
    gemm_bt<3><<<4 * 391, 512, 0, stream>>>(chb, WT, 1024, 50000, 512, 391, nullptr,
                                            expb, nullptr, rsum);
    k_finalize2<<<1024, 256, 0, stream>>>(expb, rsum, cp_all, aual, sv, out);
  } else {
    gemm_bt<1><<<4 * 391, 512, 0, stream>>>(chb, WT, 1024, 50000, 512, 391, nullptr,
                                            nullptr, out, rsum);
    k_finalize<<<1024, 256, 0, stream>>>(out, rsum, cp_all, aual, sv);
  }
}